// Round 1
// baseline (665.273 us; speedup 1.0000x reference)
//
#include <hip/hip_runtime.h>
#include <hip/hip_bf16.h>
#include <cstdint>
#include <cstddef>

// ---------------- constants ----------------
// B=2 T=1024 H=4096 HK=8 HV=32 DK=64 DV=64 VPK=4
// GEMM1: A[2048][4096] * Wt1[5248(pad 5184)][4096]^T -> qkvz[2048][5184]
// GEMM2: on[2048][2048] * Wt2[4096][2048]^T -> out[2048][4096] (fp32)
// Scan: chunked delta rule, chunk C=64, units = b(2) x hv(32) x chunk(16)

typedef __attribute__((ext_vector_type(8))) short short8;
typedef __attribute__((ext_vector_type(4))) float f32x4;

__device__ __forceinline__ short f2bf(float f) {
  union { float f; unsigned u; } x; x.f = f;
  unsigned r = x.u + 0x7fffu + ((x.u >> 16) & 1u);
  return (short)(r >> 16);
}

__device__ __forceinline__ void gl_lds16(const short* g, short* l) {
  __builtin_amdgcn_global_load_lds(
      (const __attribute__((address_space(1))) void*)g,
      (__attribute__((address_space(3))) void*)l, 16, 0, 0);
}

// ---------------- elementwise fp32 -> bf16 ----------------
__global__ __launch_bounds__(256) void to_bf16_kernel(const float* __restrict__ x,
                                                      short* __restrict__ y) {
  int i = blockIdx.x * 256 + threadIdx.x;   // one float4 per thread
  float4 v = ((const float4*)x)[i];
  ushort4 r;
  r.x = (unsigned short)f2bf(v.x);
  r.y = (unsigned short)f2bf(v.y);
  r.z = (unsigned short)f2bf(v.z);
  r.w = (unsigned short)f2bf(v.w);
  ((ushort4*)y)[i] = r;
}

// ---------------- transpose+convert W_qkvz|W_ba -> Wt1[n][k], pad to 5248 ----------------
__global__ __launch_bounds__(256) void transpose_w1(const float* __restrict__ Wq,
                                                    const float* __restrict__ Wba,
                                                    short* __restrict__ Wt) {
  __shared__ float tile[32][33];
  int n0 = blockIdx.x * 32;  // < 5248
  int k0 = blockIdx.y * 32;  // < 4096
  int t = threadIdx.x;
  int r = t >> 5;    // 0..7
  int c = t & 31;
#pragma unroll
  for (int i = 0; i < 4; ++i) {
    int kl = r + i * 8;
    int n = n0 + c;
    float v = 0.f;
    if (n < 5120) v = Wq[(size_t)(k0 + kl) * 5120 + n];
    else if (n < 5184) v = Wba[(size_t)(k0 + kl) * 64 + (n - 5120)];
    tile[kl][c] = v;
  }
  __syncthreads();
#pragma unroll
  for (int i = 0; i < 4; ++i) {
    int nl = r + i * 8;
    int kl = c;
    Wt[(size_t)(n0 + nl) * 4096 + k0 + kl] = f2bf(tile[kl][nl]);
  }
}

// ---------------- transpose+convert W_out -> Wt2[n][k] ----------------
__global__ __launch_bounds__(256) void transpose_w2(const float* __restrict__ W,
                                                    short* __restrict__ Wt) {
  __shared__ float tile[32][33];
  int n0 = blockIdx.x * 32;  // < 4096
  int k0 = blockIdx.y * 32;  // < 2048
  int t = threadIdx.x;
  int r = t >> 5;
  int c = t & 31;
#pragma unroll
  for (int i = 0; i < 4; ++i) {
    int kl = r + i * 8;
    tile[kl][c] = W[(size_t)(k0 + kl) * 4096 + n0 + c];
  }
  __syncthreads();
#pragma unroll
  for (int i = 0; i < 4; ++i) {
    int nl = r + i * 8;
    int kl = c;
    Wt[(size_t)(n0 + nl) * 2048 + k0 + kl] = f2bf(tile[kl][nl]);
  }
}

// ---------------- m97-style 128x128 bf16 MFMA GEMM, fp32 out ----------------
template <bool GUARD_N>
__global__ __launch_bounds__(256) void gemm128(const short* __restrict__ A,
                                               const short* __restrict__ Bt,
                                               float* __restrict__ C,
                                               int M, int N, int K) {
  __shared__ __align__(16) short As[128 * 32];
  __shared__ __align__(16) short Bs[128 * 32];
  const int tid = threadIdx.x;
  const int wave = tid >> 6;
  const int lane = tid & 63;
  const int m0 = blockIdx.x * 128;
  const int n0 = blockIdx.y * 128;
  const int wm = (wave >> 1) << 6;
  const int wn = (wave & 1) << 6;

  const int srow = (wave << 4) + (lane >> 2);
  const int scol = (lane & 3) << 3;
  const short* Ag = A + (size_t)(m0 + srow) * K + scol;
  const short* Bg = Bt + (size_t)(n0 + srow) * K + scol;
  const size_t rstep = (size_t)64 * K;

  const int fr = lane & 15;
  const int kq = (lane >> 4) << 3;

  f32x4 acc[4][4];
#pragma unroll
  for (int i = 0; i < 4; ++i)
#pragma unroll
    for (int j = 0; j < 4; ++j) acc[i][j] = (f32x4){0.f, 0.f, 0.f, 0.f};

  for (int k0 = 0; k0 < K; k0 += 32) {
    __syncthreads();
    gl_lds16(Ag + k0,         &As[wave * 512]);
    gl_lds16(Ag + rstep + k0, &As[2048 + wave * 512]);
    gl_lds16(Bg + k0,         &Bs[wave * 512]);
    gl_lds16(Bg + rstep + k0, &Bs[2048 + wave * 512]);
    __syncthreads();
    short8 af[4], bf[4];
#pragma unroll
    for (int i = 0; i < 4; ++i) {
      af[i] = *(const short8*)&As[(wm + i * 16 + fr) * 32 + kq];
      bf[i] = *(const short8*)&Bs[(wn + i * 16 + fr) * 32 + kq];
    }
#pragma unroll
    for (int mt = 0; mt < 4; ++mt)
#pragma unroll
      for (int nt = 0; nt < 4; ++nt)
        acc[mt][nt] = __builtin_amdgcn_mfma_f32_16x16x32_bf16(af[mt], bf[nt], acc[mt][nt], 0, 0, 0);
  }

  const int rbase = (lane >> 4) << 2;
#pragma unroll
  for (int mt = 0; mt < 4; ++mt) {
#pragma unroll
    for (int nt = 0; nt < 4; ++nt) {
      int ncol = n0 + wn + nt * 16 + fr;
      if (GUARD_N && ncol >= N) continue;
      int mrow = m0 + wm + mt * 16 + rbase;
#pragma unroll
      for (int r = 0; r < 4; ++r)
        C[(size_t)(mrow + r) * N + ncol] = acc[mt][nt][r];
    }
  }
}

// ---------------- conv(4-tap causal) + silu + l2norm(q,k) ----------------
__global__ __launch_bounds__(256) void conv_kernel(const float* __restrict__ qkvz,
                                                   const float* __restrict__ conv_w,
                                                   float* __restrict__ mix) {
  __shared__ float sq[1024];
  __shared__ float scale[16];
  int bt = blockIdx.x;       // b*1024 + t
  int t = bt & 1023;
  int tid = threadIdx.x;
  for (int c = tid; c < 3072; c += 256) {
    int col;
    if (c < 512) {
      col = (c >> 6) * 640 + (c & 63);
    } else if (c < 1024) {
      int c2 = c - 512;
      col = (c2 >> 6) * 640 + 64 + (c2 & 63);
    } else {
      int c3 = c - 1024;
      int hv = c3 >> 6;
      col = (hv >> 2) * 640 + 128 + (hv & 3) * 64 + (c3 & 63);
    }
    float acc = 0.f;
#pragma unroll
    for (int j = 0; j < 4; ++j) {
      int tt = t - 3 + j;
      if (tt >= 0) acc += qkvz[(size_t)(bt - 3 + j) * 5184 + col] * conv_w[c * 4 + j];
    }
    float sv = acc / (1.f + __expf(-acc));  // silu
    if (c < 1024)
      sq[c] = sv;
    else
      mix[(size_t)bt * 3072 + c] = sv;
  }
  __syncthreads();
  int g = tid >> 4, l = tid & 15;
  float p = 0.f;
#pragma unroll
  for (int i = 0; i < 4; ++i) {
    float v = sq[g * 64 + l * 4 + i];
    p += v * v;
  }
  p += __shfl_xor(p, 1);
  p += __shfl_xor(p, 2);
  p += __shfl_xor(p, 4);
  p += __shfl_xor(p, 8);
  if (l == 0) scale[g] = rsqrtf(p + 1e-6f);
  __syncthreads();
  for (int c = tid; c < 1024; c += 256) {
    float s = scale[c >> 6] * ((c < 512) ? 0.125f : 1.f);  // q gets DK^-0.5
    mix[(size_t)bt * 3072 + c] = sq[c] * s;
  }
}

// ---------------- gates: g (log-decay) and beta = sigmoid(b) ----------------
__global__ __launch_bounds__(256) void gate_kernel(const float* __restrict__ qkvz,
                                                   const float* __restrict__ dt_bias,
                                                   const float* __restrict__ A_log,
                                                   float* __restrict__ gb,
                                                   float* __restrict__ beta) {
  int i = blockIdx.x * 256 + threadIdx.x;  // < 65536 = 2048*32
  int hv = i & 31;
  int bt = i >> 5;
  int hk = hv >> 2, vp = hv & 3;
  const float* row = qkvz + (size_t)bt * 5184 + 5120 + hk * 8;
  float bv = row[vp];
  float av = row[4 + vp];
  float x = av + dt_bias[hv];
  float sp = (x > 20.f) ? x : log1pf(expf(x));
  gb[i] = -expf(A_log[hv]) * sp;        // log-decay g_t (<= 0)
  beta[i] = 1.f / (1.f + expf(-bv));
}

// ---------------- chunked delta-rule precompute ----------------
__global__ __launch_bounds__(256) void precompute_kernel(
    const float* __restrict__ mix, const float* __restrict__ gbuf,
    const float* __restrict__ betab, float* __restrict__ Wbuf,
    float* __restrict__ Pbuf, float* __restrict__ Rbuf, float* __restrict__ cbuf) {
  __shared__ float Kt[64][68];   // K col-major: Kt[d][t]; later K' row-major scaled
  __shared__ float Vb[64][68];   // V row-major
  __shared__ float AM[64][68];   // A; later Q col-major
  __shared__ float Mm[64][68];   // (I+A)^{-1}
  __shared__ float Tb[16][17];
  __shared__ float cs[64], bb[64];

  const int u = blockIdx.x;
  const int chunk = u & 15, hv = (u >> 4) & 31, b = u >> 9;
  const int hk = hv >> 2;
  const int t0g = b * 1024 + chunk * 64;
  const int tid = threadIdx.x;
  const int tr = tid >> 2, q4 = tid & 3;

  {
    const float* mrow = mix + (size_t)(t0g + tr) * 3072;
#pragma unroll
    for (int e = 0; e < 4; ++e) {
      int c0 = q4 * 16 + e * 4;
      float4 kv = *(const float4*)(mrow + 512 + hk * 64 + c0);
      Kt[c0 + 0][tr] = kv.x; Kt[c0 + 1][tr] = kv.y;
      Kt[c0 + 2][tr] = kv.z; Kt[c0 + 3][tr] = kv.w;
      *(float4*)&Vb[tr][c0] = *(const float4*)(mrow + 1024 + hv * 64 + c0);
    }
  }
  if (tid < 64) {
    cs[tid] = gbuf[(size_t)(t0g + tid) * 32 + hv];
    bb[tid] = betab[(size_t)(t0g + tid) * 32 + hv];
  }
  __syncthreads();
  for (int off = 1; off < 64; off <<= 1) {
    float v = 0.f;
    if (tid < 64 && tid >= off) v = cs[tid - off];
    __syncthreads();
    if (tid < 64) cs[tid] += v;
    __syncthreads();
  }
  if (tid < 64) cbuf[(size_t)u * 64 + tid] = cs[tid];

  {
    float acc[16];
#pragma unroll
    for (int i = 0; i < 16; ++i) acc[i] = 0.f;
    for (int d = 0; d < 64; ++d) {
      float kv = Kt[d][tr];
#pragma unroll
      for (int e = 0; e < 4; ++e) {
        float4 ks = *(const float4*)&Kt[d][q4 * 16 + e * 4];
        acc[e * 4 + 0] += kv * ks.x; acc[e * 4 + 1] += kv * ks.y;
        acc[e * 4 + 2] += kv * ks.z; acc[e * 4 + 3] += kv * ks.w;
      }
    }
    float bt_ = bb[tr], ct_ = cs[tr];
#pragma unroll
    for (int j = 0; j < 16; ++j) {
      int s = q4 * 16 + j;
      AM[tr][s] = (s < tr) ? bt_ * acc[j] * __expf(ct_ - cs[s]) : 0.f;
    }
  }
  __syncthreads();

  for (int i = tid; i < 64 * 68; i += 256) (&Mm[0][0])[i] = 0.f;
  __syncthreads();
  if (tid < 64) {
    int blk = tid >> 4, j = tid & 15, base = blk * 16;
    Mm[base][base + j] = (j == 0) ? 1.f : 0.f;
    for (int r = 1; r < 16; ++r) {
      float sum = 0.f;
      for (int s = 0; s < r; ++s) sum += AM[base + r][base + s] * Mm[base + s][base + j];
      Mm[base + r][base + j] = ((r == j) ? 1.f : 0.f) - sum;
    }
  }
  __syncthreads();
  for (int d = 1; d < 4; ++d) {
    for (int j = 0; j + d < 4; ++j) {
      int i = j + d;
      int r = tid >> 4, c = tid & 15;
      float tsum = 0.f;
      for (int kb = j; kb < i; ++kb)
        for (int uu = 0; uu < 16; ++uu)
          tsum += AM[i * 16 + r][kb * 16 + uu] * Mm[kb * 16 + uu][j * 16 + c];
      Tb[r][c] = tsum;
      __syncthreads();
      float msum = 0.f;
      for (int uu = 0; uu < 16; ++uu)
        msum += Mm[i * 16 + r][i * 16 + uu] * Tb[uu][c];
      __syncthreads();
      Mm[i * 16 + r][j * 16 + c] = -msum;
      __syncthreads();
    }
  }

  {
    const float* mrow = mix + (size_t)(t0g + tr) * 3072 + hk * 64;
#pragma unroll
    for (int e = 0; e < 4; ++e) {
      int c0 = q4 * 16 + e * 4;
      float4 qv = *(const float4*)(mrow + c0);
      AM[c0 + 0][tr] = qv.x; AM[c0 + 1][tr] = qv.y;
      AM[c0 + 2][tr] = qv.z; AM[c0 + 3][tr] = qv.w;
    }
  }
  __syncthreads();

  {
    float acc[16];
#pragma unroll
    for (int i = 0; i < 16; ++i) acc[i] = 0.f;
    for (int d = 0; d < 64; ++d) {
      float qv = AM[d][tr];
#pragma unroll
      for (int e = 0; e < 4; ++e) {
        float4 ks = *(const float4*)&Kt[d][q4 * 16 + e * 4];
        acc[e * 4 + 0] += qv * ks.x; acc[e * 4 + 1] += qv * ks.y;
        acc[e * 4 + 2] += qv * ks.z; acc[e * 4 + 3] += qv * ks.w;
      }
    }
    float ct_ = cs[tr];
#pragma unroll
    for (int e = 0; e < 4; ++e) {
      int s0 = q4 * 16 + e * 4;
      float4 pv;
      pv.x = (s0 + 0 <= tr) ? acc[e * 4 + 0] * __expf(ct_ - cs[s0 + 0]) : 0.f;
      pv.y = (s0 + 1 <= tr) ? acc[e * 4 + 1] * __expf(ct_ - cs[s0 + 1]) : 0.f;
      pv.z = (s0 + 2 <= tr) ? acc[e * 4 + 2] * __expf(ct_ - cs[s0 + 2]) : 0.f;
      pv.w = (s0 + 3 <= tr) ? acc[e * 4 + 3] * __expf(ct_ - cs[s0 + 3]) : 0.f;
      *(float4*)&Pbuf[(size_t)u * 4096 + tr * 64 + s0] = pv;
    }
  }
  __syncthreads();

  {
    float vals[16];
#pragma unroll
    for (int j = 0; j < 16; ++j) vals[j] = Kt[q4 * 16 + j][tr];
    float sc = bb[tr] * __expf(cs[tr]);
    __syncthreads();
#pragma unroll
    for (int j = 0; j < 16; ++j) Kt[tr][q4 * 16 + j] = vals[j] * sc;
  }
  __syncthreads();

  {
    float acc[16];
#pragma unroll
    for (int i = 0; i < 16; ++i) acc[i] = 0.f;
    for (int s = 0; s < 64; ++s) {
      float m = Mm[tr][s];
#pragma unroll
      for (int e = 0; e < 4; ++e) {
        float4 kk = *(const float4*)&Kt[s][q4 * 16 + e * 4];
        acc[e * 4 + 0] += m * kk.x; acc[e * 4 + 1] += m * kk.y;
        acc[e * 4 + 2] += m * kk.z; acc[e * 4 + 3] += m * kk.w;
      }
    }
#pragma unroll
    for (int e = 0; e < 4; ++e) {
      float4 wv = {acc[e * 4 + 0], acc[e * 4 + 1], acc[e * 4 + 2], acc[e * 4 + 3]};
      *(float4*)&Wbuf[(size_t)u * 4096 + tr * 64 + q4 * 16 + e * 4] = wv;
    }
  }
  {
    float acc[16];
#pragma unroll
    for (int i = 0; i < 16; ++i) acc[i] = 0.f;
    for (int s = 0; s < 64; ++s) {
      float m = Mm[tr][s] * bb[s];
#pragma unroll
      for (int e = 0; e < 4; ++e) {
        float4 vv = *(const float4*)&Vb[s][q4 * 16 + e * 4];
        acc[e * 4 + 0] += m * vv.x; acc[e * 4 + 1] += m * vv.y;
        acc[e * 4 + 2] += m * vv.z; acc[e * 4 + 3] += m * vv.w;
      }
    }
#pragma unroll
    for (int e = 0; e < 4; ++e) {
      float4 rv = {acc[e * 4 + 0], acc[e * 4 + 1], acc[e * 4 + 2], acc[e * 4 + 3]};
      *(float4*)&Rbuf[(size_t)u * 4096 + tr * 64 + q4 * 16 + e * 4] = rv;
    }
  }
}

// ---------------- chunked serial scan ----------------
// 512 threads = 8 waves (2/SIMD) for latency hiding.  Thread = (tr 0..63, q8 0..7),
// each thread owns a float2 of the 64x16 (vs-slice) output tile.
// o is written in block-local layout o[(bh*4+vs)][t][16] -> contiguous 512B/wave stores.
__global__ __launch_bounds__(512) void chunk_scan_kernel(
    const float* __restrict__ mix, const float* __restrict__ Wbuf,
    const float* __restrict__ Pbuf, const float* __restrict__ Rbuf,
    const float* __restrict__ cbuf, float* __restrict__ o) {
  __shared__ float Wb[64][68], Pb[64][68], Kr[64][68], Qr[64][68];
  __shared__ float S[64][16], Db[64][16];
  __shared__ float cs[64], sQ[64], sK[64];

  const int bid = blockIdx.x;
  const int vs = bid & 3, hv = (bid >> 2) & 31, b = bid >> 7;
  const int hk = hv >> 2;
  const int bh = b * 32 + hv;
  const int ubase = bh * 16;
  const int tid = threadIdx.x;
  const int tr = tid >> 3, q8 = tid & 7;

  ((float2*)S)[tid] = (float2){0.f, 0.f};

  float4 WN[2], PN[2], KN[2], QN[2];
  float2 RN;
  float cN = 0.f;

#define ISSUE_LOADS(c)                                                          \
  {                                                                             \
    size_t uu = (size_t)(ubase + (c));                                          \
    _Pragma("unroll") for (int i = 0; i < 2; ++i) {                             \
      WN[i] = ((const float4*)(Wbuf + uu * 4096))[tid + 512 * i];               \
      PN[i] = ((const float4*)(Pbuf + uu * 4096))[tid + 512 * i];               \
    }                                                                           \
    const float* mrow = mix + (size_t)(b * 1024 + (c) * 64 + tr) * 3072;        \
    _Pragma("unroll") for (int e = 0; e < 2; ++e) {                             \
      KN[e] = *(const float4*)(mrow + 512 + hk * 64 + q8 * 8 + e * 4);          \
      QN[e] = *(const float4*)(mrow + hk * 64 + q8 * 8 + e * 4);                \
    }                                                                           \
    RN = *(const float2*)(Rbuf + uu * 4096 + tr * 64 + vs * 16 + q8 * 2);       \
    if (tid < 64) cN = cbuf[uu * 64 + tid];                                     \
  }

#define COMMIT()                                                                \
  {                                                                             \
    _Pragma("unroll") for (int i = 0; i < 2; ++i) {                             \
      int flat = (tid + 512 * i) * 4;                                           \
      int r = flat >> 6, c0 = flat & 63;                                        \
      *(float4*)&Wb[r][c0] = WN[i];                                             \
      *(float4*)&Pb[r][c0] = PN[i];                                             \
    }                                                                           \
    _Pragma("unroll") for (int e = 0; e < 2; ++e) {                             \
      *(float4*)&Kr[tr][q8 * 8 + e * 4] = KN[e];                                \
      *(float4*)&Qr[tr][q8 * 8 + e * 4] = QN[e];                                \
    }                                                                           \
    if (tid < 64) cs[tid] = cN;                                                 \
    __syncthreads();                                                            \
    if (tid < 64) {                                                             \
      sQ[tid] = __expf(cs[tid]);                                                \
      sK[tid] = __expf(cs[63] - cs[tid]);                                       \
    }                                                                           \
    __syncthreads();                                                            \
  }

  ISSUE_LOADS(0);
  COMMIT();
  float2 Rv = RN;

  for (int c = 0; c < 16; ++c) {
    if (c < 15) ISSUE_LOADS(c + 1);
    // D = R - W @ S   (64x2 slice per thread)
    float2 acc = Rv;
    for (int k = 0; k < 64; ++k) {
      float w = Wb[tr][k];
      float2 s2 = *(const float2*)&S[k][q8 * 2];
      acc.x -= w * s2.x; acc.y -= w * s2.y;
    }
    *(float2*)&Db[tr][q8 * 2] = acc;
    __syncthreads();
    // O = P @ D + (Q*sQ) @ S
    {
      float sqv = sQ[tr];
      float2 ao = {0.f, 0.f};
      for (int i = 0; i < 64; ++i) {
        float p = Pb[tr][i];
        float2 d2 = *(const float2*)&Db[i][q8 * 2];
        float qv = Qr[tr][i] * sqv;
        float2 s2 = *(const float2*)&S[i][q8 * 2];
        ao.x += p * d2.x + qv * s2.x;
        ao.y += p * d2.y + qv * s2.y;
      }
      // block-local layout: o[(bh*4+vs)][c*64+tr][q8*2..]
      *(float2*)&o[((size_t)(bh * 4 + vs) * 1024 + c * 64 + tr) * 16 + q8 * 2] = ao;
    }
    __syncthreads();
    // S' = e63 * S + Khat^T @ D
    {
      float e63 = __expf(cs[63]);
      float2 sv = *(const float2*)&S[tr][q8 * 2];
      sv.x *= e63; sv.y *= e63;
      for (int s = 0; s < 64; ++s) {
        float kh = Kr[s][tr] * sK[s];
        float2 d2 = *(const float2*)&Db[s][q8 * 2];
        sv.x += kh * d2.x; sv.y += kh * d2.y;
      }
      *(float2*)&S[tr][q8 * 2] = sv;
    }
    __syncthreads();
    if (c < 15) {
      COMMIT();
      Rv = RN;
    }
  }
#undef ISSUE_LOADS
#undef COMMIT
}

// ---------------- rmsnorm * norm_w * silu(z), -> bf16 ----------------
// reads o in block-local layout o[(bh*4+vs)][t][16]; writes on[bt][hv*64+d] (standard)
__global__ __launch_bounds__(256) void rms_gate_kernel(const float* __restrict__ o,
                                                       const float* __restrict__ qkvz,
                                                       const float* __restrict__ norm_w,
                                                       short* __restrict__ on) {
  int bid = blockIdx.x;            // (bh)*256 + tgroup
  int bh = bid >> 8;               // b*32+hv
  int tg = bid & 255;
  int b = bh >> 5, hv = bh & 31;
  int t = tg * 4 + (threadIdx.x >> 6);
  int d = threadIdx.x & 63;
  int bt = b * 1024 + t;
  int hk = hv >> 2, vp = hv & 3;
  float x = o[((size_t)(bh * 4 + (d >> 4)) * 1024 + t) * 16 + (d & 15)];
  float ss = x * x;
  ss += __shfl_xor(ss, 1);
  ss += __shfl_xor(ss, 2);
  ss += __shfl_xor(ss, 4);
  ss += __shfl_xor(ss, 8);
  ss += __shfl_xor(ss, 16);
  ss += __shfl_xor(ss, 32);
  float sc = rsqrtf(ss * (1.f / 64.f) + 1e-5f);
  float z = qkvz[(size_t)bt * 5184 + hk * 640 + 384 + vp * 64 + d];
  float val = x * sc * norm_w[d] * (z / (1.f + __expf(-z)));
  on[((size_t)bt * 32 + hv) * 64 + d] = f2bf(val);
}

// ---------------- launch ----------------
extern "C" void kernel_launch(void* const* d_in, const int* in_sizes, int n_in,
                              void* d_out, int out_size, void* d_ws, size_t ws_size,
                              hipStream_t stream) {
  const float* hidden = (const float*)d_in[0];
  const float* W_qkvz = (const float*)d_in[1];
  const float* W_ba = (const float*)d_in[2];
  const float* conv_w = (const float*)d_in[3];
  const float* dt_bias = (const float*)d_in[4];
  const float* A_log = (const float*)d_in[5];
  const float* norm_w = (const float*)d_in[6];
  const float* W_out = (const float*)d_in[7];
  float* out = (float*)d_out;

  char* ws = (char*)d_ws;
  short* A_bf = (short*)(ws + 0);                // 16,777,216
  short* Wt1 = (short*)(ws + 16777216);          // 42,991,616  [5248][4096] (pad)
  short* Wt2 = (short*)(ws + 59768832);          // 16,777,216  [4096][2048]
  float* qkvz = (float*)(ws + 76546048);         // 42,467,328  [2048][5184]
  float* mix = (float*)(ws + 119013376);         // 25,165,824  [2048][3072]
  float* gbuf = (float*)(ws + 144179200);        //    262,144  [2048][32]
  float* beta = (float*)(ws + 144441344);        //    262,144
  float* o = (float*)(ws + 144703488);           // 16,777,216  [256][1024][16] block-local
  short* on = (short*)(ws + 161480704);          //  8,388,608  [2048][2048]
  float* Wbuf = (float*)(ws + 169869312);        // 16,777,216  [1024][64][64]
  float* Pbuf = (float*)(ws + 186646528);        // 16,777,216
  float* Rbuf = (float*)(ws + 203423744);        // 16,777,216
  float* cbuf = (float*)(ws + 220200960);        //    262,144  [1024][64]

  to_bf16_kernel<<<8192, 256, 0, stream>>>(hidden, A_bf);
  transpose_w1<<<dim3(164, 128), 256, 0, stream>>>(W_qkvz, W_ba, Wt1);
  transpose_w2<<<dim3(128, 64), 256, 0, stream>>>(W_out, Wt2);
  gemm128<true><<<dim3(16, 41), 256, 0, stream>>>(A_bf, Wt1, qkvz, 2048, 5184, 4096);
  conv_kernel<<<2048, 256, 0, stream>>>(qkvz, conv_w, mix);
  gate_kernel<<<256, 256, 0, stream>>>(qkvz, dt_bias, A_log, gbuf, beta);
  precompute_kernel<<<1024, 256, 0, stream>>>(mix, gbuf, beta, Wbuf, Pbuf, Rbuf, cbuf);
  chunk_scan_kernel<<<256, 512, 0, stream>>>(mix, Wbuf, Pbuf, Rbuf, cbuf, o);
  rms_gate_kernel<<<16384, 256, 0, stream>>>(o, qkvz, norm_w, on);
  gemm128<false><<<dim3(16, 32), 256, 0, stream>>>(on, Wt2, out, 2048, 4096, 2048);
}

// Round 2
// 610.704 us; speedup vs baseline: 1.0894x; 1.0894x over previous
//
#include <hip/hip_runtime.h>
#include <hip/hip_bf16.h>
#include <cstdint>
#include <cstddef>

// ---------------- constants ----------------
// B=2 T=1024 H=4096 HK=8 HV=32 DK=64 DV=64 VPK=4
// GEMM1: A[2048][4096] * Wt1[5248(pad 5184)][4096]^T -> qkvz[2048][5184]
// GEMM2: on[2048][2048] * Wt2[4096][2048]^T -> out[2048][4096] (fp32)
// Scan: chunked delta rule, chunk C=64, units = b(2) x hv(32) x chunk(16)

typedef __attribute__((ext_vector_type(8))) short short8;
typedef __attribute__((ext_vector_type(4))) float f32x4;

__device__ __forceinline__ short f2bf(float f) {
  union { float f; unsigned u; } x; x.f = f;
  unsigned r = x.u + 0x7fffu + ((x.u >> 16) & 1u);
  return (short)(r >> 16);
}

__device__ __forceinline__ void gl_lds16(const short* g, short* l) {
  __builtin_amdgcn_global_load_lds(
      (const __attribute__((address_space(1))) void*)g,
      (__attribute__((address_space(3))) void*)l, 16, 0, 0);
}

// ---------------- elementwise fp32 -> bf16 ----------------
__global__ __launch_bounds__(256) void to_bf16_kernel(const float* __restrict__ x,
                                                      short* __restrict__ y) {
  int i = blockIdx.x * 256 + threadIdx.x;   // one float4 per thread
  float4 v = ((const float4*)x)[i];
  ushort4 r;
  r.x = (unsigned short)f2bf(v.x);
  r.y = (unsigned short)f2bf(v.y);
  r.z = (unsigned short)f2bf(v.z);
  r.w = (unsigned short)f2bf(v.w);
  ((ushort4*)y)[i] = r;
}

// ---------------- transpose+convert W_qkvz|W_ba -> Wt1[n][k], pad to 5248 ----------------
__global__ __launch_bounds__(256) void transpose_w1(const float* __restrict__ Wq,
                                                    const float* __restrict__ Wba,
                                                    short* __restrict__ Wt) {
  __shared__ float tile[32][33];
  int n0 = blockIdx.x * 32;  // < 5248
  int k0 = blockIdx.y * 32;  // < 4096
  int t = threadIdx.x;
  int r = t >> 5;    // 0..7
  int c = t & 31;
#pragma unroll
  for (int i = 0; i < 4; ++i) {
    int kl = r + i * 8;
    int n = n0 + c;
    float v = 0.f;
    if (n < 5120) v = Wq[(size_t)(k0 + kl) * 5120 + n];
    else if (n < 5184) v = Wba[(size_t)(k0 + kl) * 64 + (n - 5120)];
    tile[kl][c] = v;
  }
  __syncthreads();
#pragma unroll
  for (int i = 0; i < 4; ++i) {
    int nl = r + i * 8;
    int kl = c;
    Wt[(size_t)(n0 + nl) * 4096 + k0 + kl] = f2bf(tile[kl][nl]);
  }
}

// ---------------- transpose+convert W_out -> Wt2[n][k] ----------------
__global__ __launch_bounds__(256) void transpose_w2(const float* __restrict__ W,
                                                    short* __restrict__ Wt) {
  __shared__ float tile[32][33];
  int n0 = blockIdx.x * 32;  // < 4096
  int k0 = blockIdx.y * 32;  // < 2048
  int t = threadIdx.x;
  int r = t >> 5;
  int c = t & 31;
#pragma unroll
  for (int i = 0; i < 4; ++i) {
    int kl = r + i * 8;
    tile[kl][c] = W[(size_t)(k0 + kl) * 4096 + n0 + c];
  }
  __syncthreads();
#pragma unroll
  for (int i = 0; i < 4; ++i) {
    int nl = r + i * 8;
    int kl = c;
    Wt[(size_t)(n0 + nl) * 2048 + k0 + kl] = f2bf(tile[kl][nl]);
  }
}

// ---------------- m97-style 128x128 bf16 MFMA GEMM, fp32 out ----------------
template <bool GUARD_N>
__global__ __launch_bounds__(256) void gemm128(const short* __restrict__ A,
                                               const short* __restrict__ Bt,
                                               float* __restrict__ C,
                                               int M, int N, int K) {
  __shared__ __align__(16) short As[128 * 32];
  __shared__ __align__(16) short Bs[128 * 32];
  const int tid = threadIdx.x;
  const int wave = tid >> 6;
  const int lane = tid & 63;
  const int m0 = blockIdx.x * 128;
  const int n0 = blockIdx.y * 128;
  const int wm = (wave >> 1) << 6;
  const int wn = (wave & 1) << 6;

  const int srow = (wave << 4) + (lane >> 2);
  const int scol = (lane & 3) << 3;
  const short* Ag = A + (size_t)(m0 + srow) * K + scol;
  const short* Bg = Bt + (size_t)(n0 + srow) * K + scol;
  const size_t rstep = (size_t)64 * K;

  const int fr = lane & 15;
  const int kq = (lane >> 4) << 3;

  f32x4 acc[4][4];
#pragma unroll
  for (int i = 0; i < 4; ++i)
#pragma unroll
    for (int j = 0; j < 4; ++j) acc[i][j] = (f32x4){0.f, 0.f, 0.f, 0.f};

  for (int k0 = 0; k0 < K; k0 += 32) {
    __syncthreads();
    gl_lds16(Ag + k0,         &As[wave * 512]);
    gl_lds16(Ag + rstep + k0, &As[2048 + wave * 512]);
    gl_lds16(Bg + k0,         &Bs[wave * 512]);
    gl_lds16(Bg + rstep + k0, &Bs[2048 + wave * 512]);
    __syncthreads();
    short8 af[4], bf[4];
#pragma unroll
    for (int i = 0; i < 4; ++i) {
      af[i] = *(const short8*)&As[(wm + i * 16 + fr) * 32 + kq];
      bf[i] = *(const short8*)&Bs[(wn + i * 16 + fr) * 32 + kq];
    }
#pragma unroll
    for (int mt = 0; mt < 4; ++mt)
#pragma unroll
      for (int nt = 0; nt < 4; ++nt)
        acc[mt][nt] = __builtin_amdgcn_mfma_f32_16x16x32_bf16(af[mt], bf[nt], acc[mt][nt], 0, 0, 0);
  }

  const int rbase = (lane >> 4) << 2;
#pragma unroll
  for (int mt = 0; mt < 4; ++mt) {
#pragma unroll
    for (int nt = 0; nt < 4; ++nt) {
      int ncol = n0 + wn + nt * 16 + fr;
      if (GUARD_N && ncol >= N) continue;
      int mrow = m0 + wm + mt * 16 + rbase;
#pragma unroll
      for (int r = 0; r < 4; ++r)
        C[(size_t)(mrow + r) * N + ncol] = acc[mt][nt][r];
    }
  }
}

// ---------------- conv(4-tap causal) + silu + l2norm(q,k) ----------------
__global__ __launch_bounds__(256) void conv_kernel(const float* __restrict__ qkvz,
                                                   const float* __restrict__ conv_w,
                                                   float* __restrict__ mix) {
  __shared__ float sq[1024];
  __shared__ float scale[16];
  int bt = blockIdx.x;       // b*1024 + t
  int t = bt & 1023;
  int tid = threadIdx.x;
  for (int c = tid; c < 3072; c += 256) {
    int col;
    if (c < 512) {
      col = (c >> 6) * 640 + (c & 63);
    } else if (c < 1024) {
      int c2 = c - 512;
      col = (c2 >> 6) * 640 + 64 + (c2 & 63);
    } else {
      int c3 = c - 1024;
      int hv = c3 >> 6;
      col = (hv >> 2) * 640 + 128 + (hv & 3) * 64 + (c3 & 63);
    }
    float acc = 0.f;
#pragma unroll
    for (int j = 0; j < 4; ++j) {
      int tt = t - 3 + j;
      if (tt >= 0) acc += qkvz[(size_t)(bt - 3 + j) * 5184 + col] * conv_w[c * 4 + j];
    }
    float sv = acc / (1.f + __expf(-acc));  // silu
    if (c < 1024)
      sq[c] = sv;
    else
      mix[(size_t)bt * 3072 + c] = sv;
  }
  __syncthreads();
  int g = tid >> 4, l = tid & 15;
  float p = 0.f;
#pragma unroll
  for (int i = 0; i < 4; ++i) {
    float v = sq[g * 64 + l * 4 + i];
    p += v * v;
  }
  p += __shfl_xor(p, 1);
  p += __shfl_xor(p, 2);
  p += __shfl_xor(p, 4);
  p += __shfl_xor(p, 8);
  if (l == 0) scale[g] = rsqrtf(p + 1e-6f);
  __syncthreads();
  for (int c = tid; c < 1024; c += 256) {
    float s = scale[c >> 6] * ((c < 512) ? 0.125f : 1.f);  // q gets DK^-0.5
    mix[(size_t)bt * 3072 + c] = sq[c] * s;
  }
}

// ---------------- gates: g (log-decay) and beta = sigmoid(b) ----------------
__global__ __launch_bounds__(256) void gate_kernel(const float* __restrict__ qkvz,
                                                   const float* __restrict__ dt_bias,
                                                   const float* __restrict__ A_log,
                                                   float* __restrict__ gb,
                                                   float* __restrict__ beta) {
  int i = blockIdx.x * 256 + threadIdx.x;  // < 65536 = 2048*32
  int hv = i & 31;
  int bt = i >> 5;
  int hk = hv >> 2, vp = hv & 3;
  const float* row = qkvz + (size_t)bt * 5184 + 5120 + hk * 8;
  float bv = row[vp];
  float av = row[4 + vp];
  float x = av + dt_bias[hv];
  float sp = (x > 20.f) ? x : log1pf(expf(x));
  gb[i] = -expf(A_log[hv]) * sp;        // log-decay g_t (<= 0)
  beta[i] = 1.f / (1.f + expf(-bv));
}

// ---------------- chunked delta-rule precompute ----------------
__global__ __launch_bounds__(256) void precompute_kernel(
    const float* __restrict__ mix, const float* __restrict__ gbuf,
    const float* __restrict__ betab, float* __restrict__ Wbuf,
    float* __restrict__ Pbuf, float* __restrict__ Rbuf, float* __restrict__ cbuf) {
  __shared__ float Kt[64][68];   // K col-major: Kt[d][t]; later K' row-major scaled
  __shared__ float Vb[64][68];   // V row-major
  __shared__ float AM[64][68];   // A; later Q col-major
  __shared__ float Mm[64][68];   // (I+A)^{-1}
  __shared__ float Tb[16][17];
  __shared__ float cs[64], bb[64];

  const int u = blockIdx.x;
  const int chunk = u & 15, hv = (u >> 4) & 31, b = u >> 9;
  const int hk = hv >> 2;
  const int t0g = b * 1024 + chunk * 64;
  const int tid = threadIdx.x;
  const int tr = tid >> 2, q4 = tid & 3;

  {
    const float* mrow = mix + (size_t)(t0g + tr) * 3072;
#pragma unroll
    for (int e = 0; e < 4; ++e) {
      int c0 = q4 * 16 + e * 4;
      float4 kv = *(const float4*)(mrow + 512 + hk * 64 + c0);
      Kt[c0 + 0][tr] = kv.x; Kt[c0 + 1][tr] = kv.y;
      Kt[c0 + 2][tr] = kv.z; Kt[c0 + 3][tr] = kv.w;
      *(float4*)&Vb[tr][c0] = *(const float4*)(mrow + 1024 + hv * 64 + c0);
    }
  }
  if (tid < 64) {
    cs[tid] = gbuf[(size_t)(t0g + tid) * 32 + hv];
    bb[tid] = betab[(size_t)(t0g + tid) * 32 + hv];
  }
  __syncthreads();
  for (int off = 1; off < 64; off <<= 1) {
    float v = 0.f;
    if (tid < 64 && tid >= off) v = cs[tid - off];
    __syncthreads();
    if (tid < 64) cs[tid] += v;
    __syncthreads();
  }
  if (tid < 64) cbuf[(size_t)u * 64 + tid] = cs[tid];

  {
    float acc[16];
#pragma unroll
    for (int i = 0; i < 16; ++i) acc[i] = 0.f;
    for (int d = 0; d < 64; ++d) {
      float kv = Kt[d][tr];
#pragma unroll
      for (int e = 0; e < 4; ++e) {
        float4 ks = *(const float4*)&Kt[d][q4 * 16 + e * 4];
        acc[e * 4 + 0] += kv * ks.x; acc[e * 4 + 1] += kv * ks.y;
        acc[e * 4 + 2] += kv * ks.z; acc[e * 4 + 3] += kv * ks.w;
      }
    }
    float bt_ = bb[tr], ct_ = cs[tr];
#pragma unroll
    for (int j = 0; j < 16; ++j) {
      int s = q4 * 16 + j;
      AM[tr][s] = (s < tr) ? bt_ * acc[j] * __expf(ct_ - cs[s]) : 0.f;
    }
  }
  __syncthreads();

  for (int i = tid; i < 64 * 68; i += 256) (&Mm[0][0])[i] = 0.f;
  __syncthreads();
  if (tid < 64) {
    int blk = tid >> 4, j = tid & 15, base = blk * 16;
    Mm[base][base + j] = (j == 0) ? 1.f : 0.f;
    for (int r = 1; r < 16; ++r) {
      float sum = 0.f;
      for (int s = 0; s < r; ++s) sum += AM[base + r][base + s] * Mm[base + s][base + j];
      Mm[base + r][base + j] = ((r == j) ? 1.f : 0.f) - sum;
    }
  }
  __syncthreads();
  for (int d = 1; d < 4; ++d) {
    for (int j = 0; j + d < 4; ++j) {
      int i = j + d;
      int r = tid >> 4, c = tid & 15;
      float tsum = 0.f;
      for (int kb = j; kb < i; ++kb)
        for (int uu = 0; uu < 16; ++uu)
          tsum += AM[i * 16 + r][kb * 16 + uu] * Mm[kb * 16 + uu][j * 16 + c];
      Tb[r][c] = tsum;
      __syncthreads();
      float msum = 0.f;
      for (int uu = 0; uu < 16; ++uu)
        msum += Mm[i * 16 + r][i * 16 + uu] * Tb[uu][c];
      __syncthreads();
      Mm[i * 16 + r][j * 16 + c] = -msum;
      __syncthreads();
    }
  }

  {
    const float* mrow = mix + (size_t)(t0g + tr) * 3072 + hk * 64;
#pragma unroll
    for (int e = 0; e < 4; ++e) {
      int c0 = q4 * 16 + e * 4;
      float4 qv = *(const float4*)(mrow + c0);
      AM[c0 + 0][tr] = qv.x; AM[c0 + 1][tr] = qv.y;
      AM[c0 + 2][tr] = qv.z; AM[c0 + 3][tr] = qv.w;
    }
  }
  __syncthreads();

  {
    float acc[16];
#pragma unroll
    for (int i = 0; i < 16; ++i) acc[i] = 0.f;
    for (int d = 0; d < 64; ++d) {
      float qv = AM[d][tr];
#pragma unroll
      for (int e = 0; e < 4; ++e) {
        float4 ks = *(const float4*)&Kt[d][q4 * 16 + e * 4];
        acc[e * 4 + 0] += qv * ks.x; acc[e * 4 + 1] += qv * ks.y;
        acc[e * 4 + 2] += qv * ks.z; acc[e * 4 + 3] += qv * ks.w;
      }
    }
    float ct_ = cs[tr];
#pragma unroll
    for (int e = 0; e < 4; ++e) {
      int s0 = q4 * 16 + e * 4;
      float4 pv;
      pv.x = (s0 + 0 <= tr) ? acc[e * 4 + 0] * __expf(ct_ - cs[s0 + 0]) : 0.f;
      pv.y = (s0 + 1 <= tr) ? acc[e * 4 + 1] * __expf(ct_ - cs[s0 + 1]) : 0.f;
      pv.z = (s0 + 2 <= tr) ? acc[e * 4 + 2] * __expf(ct_ - cs[s0 + 2]) : 0.f;
      pv.w = (s0 + 3 <= tr) ? acc[e * 4 + 3] * __expf(ct_ - cs[s0 + 3]) : 0.f;
      *(float4*)&Pbuf[(size_t)u * 4096 + tr * 64 + s0] = pv;
    }
  }
  __syncthreads();

  {
    float vals[16];
#pragma unroll
    for (int j = 0; j < 16; ++j) vals[j] = Kt[q4 * 16 + j][tr];
    float sc = bb[tr] * __expf(cs[tr]);
    __syncthreads();
#pragma unroll
    for (int j = 0; j < 16; ++j) Kt[tr][q4 * 16 + j] = vals[j] * sc;
  }
  __syncthreads();

  {
    float acc[16];
#pragma unroll
    for (int i = 0; i < 16; ++i) acc[i] = 0.f;
    for (int s = 0; s < 64; ++s) {
      float m = Mm[tr][s];
#pragma unroll
      for (int e = 0; e < 4; ++e) {
        float4 kk = *(const float4*)&Kt[s][q4 * 16 + e * 4];
        acc[e * 4 + 0] += m * kk.x; acc[e * 4 + 1] += m * kk.y;
        acc[e * 4 + 2] += m * kk.z; acc[e * 4 + 3] += m * kk.w;
      }
    }
#pragma unroll
    for (int e = 0; e < 4; ++e) {
      float4 wv = {acc[e * 4 + 0], acc[e * 4 + 1], acc[e * 4 + 2], acc[e * 4 + 3]};
      *(float4*)&Wbuf[(size_t)u * 4096 + tr * 64 + q4 * 16 + e * 4] = wv;
    }
  }
  {
    float acc[16];
#pragma unroll
    for (int i = 0; i < 16; ++i) acc[i] = 0.f;
    for (int s = 0; s < 64; ++s) {
      float m = Mm[tr][s] * bb[s];
#pragma unroll
      for (int e = 0; e < 4; ++e) {
        float4 vv = *(const float4*)&Vb[s][q4 * 16 + e * 4];
        acc[e * 4 + 0] += m * vv.x; acc[e * 4 + 1] += m * vv.y;
        acc[e * 4 + 2] += m * vv.z; acc[e * 4 + 3] += m * vv.w;
      }
    }
#pragma unroll
    for (int e = 0; e < 4; ++e) {
      float4 rv = {acc[e * 4 + 0], acc[e * 4 + 1], acc[e * 4 + 2], acc[e * 4 + 3]};
      *(float4*)&Rbuf[(size_t)u * 4096 + tr * 64 + q4 * 16 + e * 4] = rv;
    }
  }
}

// ---------------- chunked serial scan ----------------
// 512 threads = 8 waves.  Thread = (tr 0..63, q8 0..7); owns 2 cols {2q8, 2q8+1}
// of the 64x16 vs-slice.  All per-chunk operands stored so inner loops read
// contiguous float4 rows:
//   Wb[t][kd], Pb[t][s], Qh[t][kd] (pre-scaled by exp(c_t)),
//   Kt[kd][t]  (transposed + pre-scaled by exp(c63-c_t)),
//   St[v][kd]  (S^T state), Dt[v][t] (D^T workspace).
__global__ __launch_bounds__(512) void chunk_scan_kernel(
    const float* __restrict__ mix, const float* __restrict__ Wbuf,
    const float* __restrict__ Pbuf, const float* __restrict__ Rbuf,
    const float* __restrict__ cbuf, float* __restrict__ o) {
  __shared__ float Wb[64][68], Pb[64][68], Qh[64][68], Kt[64][68];
  __shared__ float St[16][68], Dt[16][68];
  __shared__ float cs[64];

  const int bid = blockIdx.x;
  const int vs = bid & 3, hv = (bid >> 2) & 31, b = bid >> 7;
  const int hk = hv >> 2;
  const int bh = b * 32 + hv;
  const int ubase = bh * 16;
  const int tid = threadIdx.x;
  const int tr = tid >> 3, q8 = tid & 7;
  const int c0 = q8 * 2, c1 = q8 * 2 + 1;

  // zero S^T state
  for (int i = tid; i < 16 * 68; i += 512) (&St[0][0])[i] = 0.f;

  float4 WN[2], PN[2], KN[2], QN[2];
  float2 RN;
  float cN = 0.f;
  float e63c = 1.f;

#define ISSUE_LOADS(c)                                                          \
  {                                                                             \
    size_t uu = (size_t)(ubase + (c));                                          \
    _Pragma("unroll") for (int i = 0; i < 2; ++i) {                             \
      WN[i] = ((const float4*)(Wbuf + uu * 4096))[tid + 512 * i];               \
      PN[i] = ((const float4*)(Pbuf + uu * 4096))[tid + 512 * i];               \
    }                                                                           \
    const float* mrow = mix + (size_t)(b * 1024 + (c) * 64 + tr) * 3072;        \
    _Pragma("unroll") for (int e = 0; e < 2; ++e) {                             \
      KN[e] = *(const float4*)(mrow + 512 + hk * 64 + q8 * 8 + e * 4);          \
      QN[e] = *(const float4*)(mrow + hk * 64 + q8 * 8 + e * 4);                \
    }                                                                           \
    RN = *(const float2*)(Rbuf + uu * 4096 + tr * 64 + vs * 16 + q8 * 2);       \
    if (tid < 64) cN = cbuf[uu * 64 + tid];                                     \
  }

  // stage W,P,cs (pre-barrier); then scale+write Qh,Kt (post-barrier).
  // e63c (register) carries exp(cs[63]) of the staged chunk into its S-update.
#define COMMIT()                                                                \
  {                                                                             \
    _Pragma("unroll") for (int i = 0; i < 2; ++i) {                             \
      int flat = (tid + 512 * i) * 4;                                           \
      int rr = flat >> 6, cc = flat & 63;                                       \
      *(float4*)&Wb[rr][cc] = WN[i];                                            \
      *(float4*)&Pb[rr][cc] = PN[i];                                            \
    }                                                                           \
    if (tid < 64) cs[tid] = cN;                                                 \
    __syncthreads();                                                            \
    float csv = cs[tr], cs63 = cs[63];                                          \
    float sQv = __expf(csv), sKv = __expf(cs63 - csv);                          \
    e63c = __expf(cs63);                                                        \
    float4 qa, qb;                                                              \
    qa.x = QN[0].x * sQv; qa.y = QN[0].y * sQv;                                 \
    qa.z = QN[0].z * sQv; qa.w = QN[0].w * sQv;                                 \
    qb.x = QN[1].x * sQv; qb.y = QN[1].y * sQv;                                 \
    qb.z = QN[1].z * sQv; qb.w = QN[1].w * sQv;                                 \
    *(float4*)&Qh[tr][q8 * 8] = qa;                                             \
    *(float4*)&Qh[tr][q8 * 8 + 4] = qb;                                         \
    Kt[q8 * 8 + 0][tr] = KN[0].x * sKv;                                         \
    Kt[q8 * 8 + 1][tr] = KN[0].y * sKv;                                         \
    Kt[q8 * 8 + 2][tr] = KN[0].z * sKv;                                         \
    Kt[q8 * 8 + 3][tr] = KN[0].w * sKv;                                         \
    Kt[q8 * 8 + 4][tr] = KN[1].x * sKv;                                         \
    Kt[q8 * 8 + 5][tr] = KN[1].y * sKv;                                         \
    Kt[q8 * 8 + 6][tr] = KN[1].z * sKv;                                         \
    Kt[q8 * 8 + 7][tr] = KN[1].w * sKv;                                         \
  }

  ISSUE_LOADS(0);
  COMMIT();
  float2 Rv = RN;

  for (int c = 0; c < 16; ++c) {
    if (c < 15) ISSUE_LOADS(c + 1);
    // ---- D[t][v] = R - W @ S : acc over kd, contiguous in Wb row / St row ----
    float2 acc = Rv;
#pragma unroll 4
    for (int k = 0; k < 64; k += 4) {
      float4 w4 = *(const float4*)&Wb[tr][k];
      float4 sa = *(const float4*)&St[c0][k];
      float4 sb = *(const float4*)&St[c1][k];
      acc.x -= w4.x * sa.x + w4.y * sa.y + w4.z * sa.z + w4.w * sa.w;
      acc.y -= w4.x * sb.x + w4.y * sb.y + w4.z * sb.z + w4.w * sb.w;
    }
    Dt[c0][tr] = acc.x;
    Dt[c1][tr] = acc.y;
    __syncthreads();
    // ---- O[t][v] = P @ D + Qh @ S ----
    {
      float2 ao = {0.f, 0.f};
#pragma unroll 4
      for (int i = 0; i < 64; i += 4) {
        float4 p4 = *(const float4*)&Pb[tr][i];
        float4 q4 = *(const float4*)&Qh[tr][i];
        float4 da = *(const float4*)&Dt[c0][i];
        float4 db = *(const float4*)&Dt[c1][i];
        float4 sa = *(const float4*)&St[c0][i];
        float4 sb = *(const float4*)&St[c1][i];
        ao.x += p4.x * da.x + p4.y * da.y + p4.z * da.z + p4.w * da.w
              + q4.x * sa.x + q4.y * sa.y + q4.z * sa.z + q4.w * sa.w;
        ao.y += p4.x * db.x + p4.y * db.y + p4.z * db.z + p4.w * db.w
              + q4.x * sb.x + q4.y * sb.y + q4.z * sb.z + q4.w * sb.w;
      }
      *(float2*)&o[((size_t)(bh * 4 + vs) * 1024 + c * 64 + tr) * 16 + q8 * 2] = ao;
    }
    __syncthreads();
    // ---- S^T[v][kd] = e63*S^T + (Kt @ D^T-style row dot) ----
    {
      float sx = St[c0][tr] * e63c;
      float sy = St[c1][tr] * e63c;
#pragma unroll 4
      for (int t = 0; t < 64; t += 4) {
        float4 k4 = *(const float4*)&Kt[tr][t];
        float4 da = *(const float4*)&Dt[c0][t];
        float4 db = *(const float4*)&Dt[c1][t];
        sx += k4.x * da.x + k4.y * da.y + k4.z * da.z + k4.w * da.w;
        sy += k4.x * db.x + k4.y * db.y + k4.z * db.z + k4.w * db.w;
      }
      St[c0][tr] = sx;
      St[c1][tr] = sy;
    }
    if (c < 15) {
      COMMIT();   // internal barrier also orders St/Dt reuse across chunks
      Rv = RN;
    }
  }
#undef ISSUE_LOADS
#undef COMMIT
}

// ---------------- rmsnorm * norm_w * silu(z), -> bf16 ----------------
// reads o in block-local layout o[(bh*4+vs)][t][16]; writes on[bt][hv*64+d] (standard)
__global__ __launch_bounds__(256) void rms_gate_kernel(const float* __restrict__ o,
                                                       const float* __restrict__ qkvz,
                                                       const float* __restrict__ norm_w,
                                                       short* __restrict__ on) {
  int bid = blockIdx.x;            // (bh)*256 + tgroup
  int bh = bid >> 8;               // b*32+hv
  int tg = bid & 255;
  int b = bh >> 5, hv = bh & 31;
  int t = tg * 4 + (threadIdx.x >> 6);
  int d = threadIdx.x & 63;
  int bt = b * 1024 + t;
  int hk = hv >> 2, vp = hv & 3;
  float x = o[((size_t)(bh * 4 + (d >> 4)) * 1024 + t) * 16 + (d & 15)];
  float ss = x * x;
  ss += __shfl_xor(ss, 1);
  ss += __shfl_xor(ss, 2);
  ss += __shfl_xor(ss, 4);
  ss += __shfl_xor(ss, 8);
  ss += __shfl_xor(ss, 16);
  ss += __shfl_xor(ss, 32);
  float sc = rsqrtf(ss * (1.f / 64.f) + 1e-5f);
  float z = qkvz[(size_t)bt * 5184 + hk * 640 + 384 + vp * 64 + d];
  float val = x * sc * norm_w[d] * (z / (1.f + __expf(-z)));
  on[((size_t)bt * 32 + hv) * 64 + d] = f2bf(val);
}

// ---------------- launch ----------------
extern "C" void kernel_launch(void* const* d_in, const int* in_sizes, int n_in,
                              void* d_out, int out_size, void* d_ws, size_t ws_size,
                              hipStream_t stream) {
  const float* hidden = (const float*)d_in[0];
  const float* W_qkvz = (const float*)d_in[1];
  const float* W_ba = (const float*)d_in[2];
  const float* conv_w = (const float*)d_in[3];
  const float* dt_bias = (const float*)d_in[4];
  const float* A_log = (const float*)d_in[5];
  const float* norm_w = (const float*)d_in[6];
  const float* W_out = (const float*)d_in[7];
  float* out = (float*)d_out;

  char* ws = (char*)d_ws;
  short* A_bf = (short*)(ws + 0);                // 16,777,216
  short* Wt1 = (short*)(ws + 16777216);          // 42,991,616  [5248][4096] (pad)
  short* Wt2 = (short*)(ws + 59768832);          // 16,777,216  [4096][2048]
  float* qkvz = (float*)(ws + 76546048);         // 42,467,328  [2048][5184]
  float* mix = (float*)(ws + 119013376);         // 25,165,824  [2048][3072]
  float* gbuf = (float*)(ws + 144179200);        //    262,144  [2048][32]
  float* beta = (float*)(ws + 144441344);        //    262,144
  float* o = (float*)(ws + 144703488);           // 16,777,216  [256][1024][16] block-local
  short* on = (short*)(ws + 161480704);          //  8,388,608  [2048][2048]
  float* Wbuf = (float*)(ws + 169869312);        // 16,777,216  [1024][64][64]
  float* Pbuf = (float*)(ws + 186646528);        // 16,777,216
  float* Rbuf = (float*)(ws + 203423744);        // 16,777,216
  float* cbuf = (float*)(ws + 220200960);        //    262,144  [1024][64]

  to_bf16_kernel<<<8192, 256, 0, stream>>>(hidden, A_bf);
  transpose_w1<<<dim3(164, 128), 256, 0, stream>>>(W_qkvz, W_ba, Wt1);
  transpose_w2<<<dim3(128, 64), 256, 0, stream>>>(W_out, Wt2);
  gemm128<true><<<dim3(16, 41), 256, 0, stream>>>(A_bf, Wt1, qkvz, 2048, 5184, 4096);
  conv_kernel<<<2048, 256, 0, stream>>>(qkvz, conv_w, mix);
  gate_kernel<<<256, 256, 0, stream>>>(qkvz, dt_bias, A_log, gbuf, beta);
  precompute_kernel<<<1024, 256, 0, stream>>>(mix, gbuf, beta, Wbuf, Pbuf, Rbuf, cbuf);
  chunk_scan_kernel<<<256, 512, 0, stream>>>(mix, Wbuf, Pbuf, Rbuf, cbuf, o);
  rms_gate_kernel<<<16384, 256, 0, stream>>>(o, qkvz, norm_w, on);
  gemm128<false><<<dim3(16, 32), 256, 0, stream>>>(on, Wt2, out, 2048, 4096, 2048);
}

// Round 3
// 599.707 us; speedup vs baseline: 1.1093x; 1.0183x over previous
//
#include <hip/hip_runtime.h>
#include <hip/hip_bf16.h>
#include <cstdint>
#include <cstddef>

// ---------------- constants ----------------
// B=2 T=1024 H=4096 HK=8 HV=32 DK=64 DV=64 VPK=4
// GEMM1: A[2048][4096] * Wt1[5248(pad 5184)][4096]^T -> qkvz[2048][5184]  (gemm256)
// GEMM2: on[2048][2048] * Wt2[4096][2048]^T -> out[2048][4096] (fp32)    (gemm128)
// Scan: chunked delta rule, chunk C=64, units = b(2) x hv(32) x chunk(16)

typedef __attribute__((ext_vector_type(8))) short short8;
typedef __attribute__((ext_vector_type(4))) float f32x4;

__device__ __forceinline__ short f2bf(float f) {
  union { float f; unsigned u; } x; x.f = f;
  unsigned r = x.u + 0x7fffu + ((x.u >> 16) & 1u);
  return (short)(r >> 16);
}

__device__ __forceinline__ void gl_lds16(const short* g, short* l) {
  __builtin_amdgcn_global_load_lds(
      (const __attribute__((address_space(1))) void*)g,
      (__attribute__((address_space(3))) void*)l, 16, 0, 0);
}

// ---------------- elementwise fp32 -> bf16 ----------------
__global__ __launch_bounds__(256) void to_bf16_kernel(const float* __restrict__ x,
                                                      short* __restrict__ y) {
  int i = blockIdx.x * 256 + threadIdx.x;   // one float4 per thread
  float4 v = ((const float4*)x)[i];
  ushort4 r;
  r.x = (unsigned short)f2bf(v.x);
  r.y = (unsigned short)f2bf(v.y);
  r.z = (unsigned short)f2bf(v.z);
  r.w = (unsigned short)f2bf(v.w);
  ((ushort4*)y)[i] = r;
}

// ---------------- transpose+convert W_qkvz|W_ba -> Wt1[n][k], pad to 5248 ----------------
__global__ __launch_bounds__(256) void transpose_w1(const float* __restrict__ Wq,
                                                    const float* __restrict__ Wba,
                                                    short* __restrict__ Wt) {
  __shared__ float tile[32][33];
  int n0 = blockIdx.x * 32;  // < 5248
  int k0 = blockIdx.y * 32;  // < 4096
  int t = threadIdx.x;
  int r = t >> 5;    // 0..7
  int c = t & 31;
#pragma unroll
  for (int i = 0; i < 4; ++i) {
    int kl = r + i * 8;
    int n = n0 + c;
    float v = 0.f;
    if (n < 5120) v = Wq[(size_t)(k0 + kl) * 5120 + n];
    else if (n < 5184) v = Wba[(size_t)(k0 + kl) * 64 + (n - 5120)];
    tile[kl][c] = v;
  }
  __syncthreads();
#pragma unroll
  for (int i = 0; i < 4; ++i) {
    int nl = r + i * 8;
    int kl = c;
    Wt[(size_t)(n0 + nl) * 4096 + k0 + kl] = f2bf(tile[kl][nl]);
  }
}

// ---------------- transpose+convert W_out -> Wt2[n][k] ----------------
__global__ __launch_bounds__(256) void transpose_w2(const float* __restrict__ W,
                                                    short* __restrict__ Wt) {
  __shared__ float tile[32][33];
  int n0 = blockIdx.x * 32;  // < 4096
  int k0 = blockIdx.y * 32;  // < 2048
  int t = threadIdx.x;
  int r = t >> 5;
  int c = t & 31;
#pragma unroll
  for (int i = 0; i < 4; ++i) {
    int kl = r + i * 8;
    tile[kl][c] = W[(size_t)(k0 + kl) * 4096 + n0 + c];
  }
  __syncthreads();
#pragma unroll
  for (int i = 0; i < 4; ++i) {
    int nl = r + i * 8;
    int kl = c;
    Wt[(size_t)(n0 + nl) * 2048 + k0 + kl] = f2bf(tile[kl][nl]);
  }
}

// ---------------- 256x256 pipelined bf16 MFMA GEMM (3-stage, counted vmcnt) ----
// BM=BN=256, BK=32, 512 threads = 8 waves (2M x 4N), per-wave C = 128x64.
// LDS: 3 buffers x (A 16KB + B 16KB) = 96 KiB.  Buffer of kt = kt%3; staging of
// kt+2 writes buffer (kt+2)%3 whose last reads finished before the previous
// trailing barrier -> race-free with loads in flight (vmcnt(4), never 0).
// LDS layout: 16B slot(row, s) -> phys slot rp*8 + (((row&1)*4+s)^(rp&7)),
// rp=row>>1.  Fragment reads hit each bank-quad exactly 2x (free).  Staging
// keeps global_load_lds dest LINEAR and pre-permutes the global source.
template <bool GUARD_N>
__global__ __launch_bounds__(512) void gemm256(const short* __restrict__ A,
                                               const short* __restrict__ Bt,
                                               float* __restrict__ C,
                                               int M, int N, int K) {
  __shared__ __align__(16) short As[3 * 8192];
  __shared__ __align__(16) short Bs[3 * 8192];
  const int tid = threadIdx.x;
  const int w = tid >> 6, lane = tid & 63;
  const int wm = w >> 2, wn = w & 3;
  const int m0 = blockIdx.x * 256, n0 = blockIdx.y * 256;
  (void)M;

  // staging: phys slot p = round*512 + w*64 + lane  ->  (row, s)
  const int p0 = w * 64 + lane;
  const int rp0 = p0 >> 3, q0 = p0 & 7;
  const int mm0 = q0 ^ (rp0 & 7);
  const int srow = rp0 * 2 + (mm0 >> 2);     // 0..127 (round1 = +128)
  const int scol = (mm0 & 3) << 3;           // elem offset 0/8/16/24
  const short* Ag = A + (size_t)(m0 + srow) * K + scol;
  const short* Bg = Bt + (size_t)(n0 + srow) * K + scol;
  const size_t rstep = (size_t)128 * K;

  // fragment read offsets (shorts): row = frag base + (lane&15), s = lane>>4
  const int fr = lane & 15;
  const int s = lane >> 4;
  int aoff[8], boff[4];
#pragma unroll
  for (int i = 0; i < 8; ++i) {
    int row = wm * 128 + i * 16 + fr;
    int rp = row >> 1;
    int q = (((row & 1) << 2) | s) ^ (rp & 7);
    aoff[i] = (rp * 8 + q) * 8;
  }
#pragma unroll
  for (int j = 0; j < 4; ++j) {
    int row = wn * 64 + j * 16 + fr;
    int rp = row >> 1;
    int q = (((row & 1) << 2) | s) ^ (rp & 7);
    boff[j] = (rp * 8 + q) * 8;
  }

  f32x4 acc[8][4];
#pragma unroll
  for (int i = 0; i < 8; ++i)
#pragma unroll
    for (int j = 0; j < 4; ++j) acc[i][j] = (f32x4){0.f, 0.f, 0.f, 0.f};

  const int NKT = K >> 5;

#define STAGE_A(kt, bb)                                                \
  { const short* g = Ag + (size_t)(kt) * 32;                           \
    gl_lds16(g,         &As[(bb) * 8192 + w * 512]);                   \
    gl_lds16(g + rstep, &As[(bb) * 8192 + 4096 + w * 512]); }
#define STAGE_B(kt, bb)                                                \
  { const short* g = Bg + (size_t)(kt) * 32;                           \
    gl_lds16(g,         &Bs[(bb) * 8192 + w * 512]);                   \
    gl_lds16(g + rstep, &Bs[(bb) * 8192 + 4096 + w * 512]); }

  // prologue: stage kt0 -> buf0, kt1 -> buf1; wait kt0 resident (4 in flight ok)
  STAGE_A(0, 0); STAGE_B(0, 0);
  STAGE_A(1, 1); STAGE_B(1, 1);
  asm volatile("s_waitcnt vmcnt(4)" ::: "memory");
  __builtin_amdgcn_s_barrier();
  __builtin_amdgcn_sched_barrier(0);

  int bi = 0;
  for (int kt = 0; kt < NKT; ++kt) {
    int bi2 = bi - 1; if (bi2 < 0) bi2 = 2;   // (kt+2)%3
    const short* Ab = &As[bi * 8192];
    const short* Bb = &Bs[bi * 8192];
    short8 af[4], bf[4];
    // ---- phase 1: frags(m0-3, n0-3) + stage A(kt+2) ----
#pragma unroll
    for (int i = 0; i < 4; ++i) af[i] = *(const short8*)&Ab[aoff[i]];
#pragma unroll
    for (int j = 0; j < 4; ++j) bf[j] = *(const short8*)&Bb[boff[j]];
    if (kt + 2 < NKT) STAGE_A(kt + 2, bi2);
    __builtin_amdgcn_s_barrier();
    asm volatile("s_waitcnt lgkmcnt(0)" ::: "memory");
    __builtin_amdgcn_sched_barrier(0);
    __builtin_amdgcn_s_setprio(1);
#pragma unroll
    for (int i = 0; i < 4; ++i)
#pragma unroll
      for (int j = 0; j < 4; ++j)
        acc[i][j] = __builtin_amdgcn_mfma_f32_16x16x32_bf16(af[i], bf[j], acc[i][j], 0, 0, 0);
    __builtin_amdgcn_s_setprio(0);
    __builtin_amdgcn_sched_barrier(0);
    // ---- phase 2: frags(m4-7) + stage B(kt+2); counted vmcnt ----
#pragma unroll
    for (int i = 0; i < 4; ++i) af[i] = *(const short8*)&Ab[aoff[i + 4]];
    if (kt + 2 < NKT) STAGE_B(kt + 2, bi2);
    if (kt < NKT - 2) { asm volatile("s_waitcnt vmcnt(4)" ::: "memory"); }
    else              { asm volatile("s_waitcnt vmcnt(0)" ::: "memory"); }
    __builtin_amdgcn_s_barrier();
    asm volatile("s_waitcnt lgkmcnt(0)" ::: "memory");
    __builtin_amdgcn_sched_barrier(0);
    __builtin_amdgcn_s_setprio(1);
#pragma unroll
    for (int i = 0; i < 4; ++i)
#pragma unroll
      for (int j = 0; j < 4; ++j)
        acc[i + 4][j] = __builtin_amdgcn_mfma_f32_16x16x32_bf16(af[i], bf[j], acc[i + 4][j], 0, 0, 0);
    __builtin_amdgcn_s_setprio(0);
    __builtin_amdgcn_sched_barrier(0);
    __builtin_amdgcn_s_barrier();   // trailing: makes next-iter staging into bi safe
    ++bi; if (bi == 3) bi = 0;
  }
#undef STAGE_A
#undef STAGE_B

  // C/D layout: col = lane&15, row = (lane>>4)*4 + r
  const int rbase = (lane >> 4) << 2;
#pragma unroll
  for (int i = 0; i < 8; ++i) {
#pragma unroll
    for (int j = 0; j < 4; ++j) {
      int col = n0 + wn * 64 + j * 16 + fr;
      if (GUARD_N && col >= N) continue;
      int row = m0 + wm * 128 + i * 16 + rbase;
#pragma unroll
      for (int r = 0; r < 4; ++r)
        C[(size_t)(row + r) * N + col] = acc[i][j][r];
    }
  }
}

// ---------------- m97-style 128x128 bf16 MFMA GEMM, fp32 out ----------------
template <bool GUARD_N>
__global__ __launch_bounds__(256) void gemm128(const short* __restrict__ A,
                                               const short* __restrict__ Bt,
                                               float* __restrict__ C,
                                               int M, int N, int K) {
  __shared__ __align__(16) short As[128 * 32];
  __shared__ __align__(16) short Bs[128 * 32];
  const int tid = threadIdx.x;
  const int wave = tid >> 6;
  const int lane = tid & 63;
  const int m0 = blockIdx.x * 128;
  const int n0 = blockIdx.y * 128;
  const int wm = (wave >> 1) << 6;
  const int wn = (wave & 1) << 6;

  const int srow = (wave << 4) + (lane >> 2);
  const int scol = (lane & 3) << 3;
  const short* Ag = A + (size_t)(m0 + srow) * K + scol;
  const short* Bg = Bt + (size_t)(n0 + srow) * K + scol;
  const size_t rstep = (size_t)64 * K;

  const int fr = lane & 15;
  const int kq = (lane >> 4) << 3;

  f32x4 acc[4][4];
#pragma unroll
  for (int i = 0; i < 4; ++i)
#pragma unroll
    for (int j = 0; j < 4; ++j) acc[i][j] = (f32x4){0.f, 0.f, 0.f, 0.f};

  for (int k0 = 0; k0 < K; k0 += 32) {
    __syncthreads();
    gl_lds16(Ag + k0,         &As[wave * 512]);
    gl_lds16(Ag + rstep + k0, &As[2048 + wave * 512]);
    gl_lds16(Bg + k0,         &Bs[wave * 512]);
    gl_lds16(Bg + rstep + k0, &Bs[2048 + wave * 512]);
    __syncthreads();
    short8 af[4], bf[4];
#pragma unroll
    for (int i = 0; i < 4; ++i) {
      af[i] = *(const short8*)&As[(wm + i * 16 + fr) * 32 + kq];
      bf[i] = *(const short8*)&Bs[(wn + i * 16 + fr) * 32 + kq];
    }
#pragma unroll
    for (int mt = 0; mt < 4; ++mt)
#pragma unroll
      for (int nt = 0; nt < 4; ++nt)
        acc[mt][nt] = __builtin_amdgcn_mfma_f32_16x16x32_bf16(af[mt], bf[nt], acc[mt][nt], 0, 0, 0);
  }

  const int rbase = (lane >> 4) << 2;
#pragma unroll
  for (int mt = 0; mt < 4; ++mt) {
#pragma unroll
    for (int nt = 0; nt < 4; ++nt) {
      int ncol = n0 + wn + nt * 16 + fr;
      if (GUARD_N && ncol >= N) continue;
      int mrow = m0 + wm + mt * 16 + rbase;
#pragma unroll
      for (int r = 0; r < 4; ++r)
        C[(size_t)(mrow + r) * N + ncol] = acc[mt][nt][r];
    }
  }
}

// ---------------- conv(4-tap causal) + silu + l2norm(q,k) ----------------
__global__ __launch_bounds__(256) void conv_kernel(const float* __restrict__ qkvz,
                                                   const float* __restrict__ conv_w,
                                                   float* __restrict__ mix) {
  __shared__ float sq[1024];
  __shared__ float scale[16];
  int bt = blockIdx.x;       // b*1024 + t
  int t = bt & 1023;
  int tid = threadIdx.x;
  for (int c = tid; c < 3072; c += 256) {
    int col;
    if (c < 512) {
      col = (c >> 6) * 640 + (c & 63);
    } else if (c < 1024) {
      int c2 = c - 512;
      col = (c2 >> 6) * 640 + 64 + (c2 & 63);
    } else {
      int c3 = c - 1024;
      int hv = c3 >> 6;
      col = (hv >> 2) * 640 + 128 + (hv & 3) * 64 + (c3 & 63);
    }
    float acc = 0.f;
#pragma unroll
    for (int j = 0; j < 4; ++j) {
      int tt = t - 3 + j;
      if (tt >= 0) acc += qkvz[(size_t)(bt - 3 + j) * 5184 + col] * conv_w[c * 4 + j];
    }
    float sv = acc / (1.f + __expf(-acc));  // silu
    if (c < 1024)
      sq[c] = sv;
    else
      mix[(size_t)bt * 3072 + c] = sv;
  }
  __syncthreads();
  int g = tid >> 4, l = tid & 15;
  float p = 0.f;
#pragma unroll
  for (int i = 0; i < 4; ++i) {
    float v = sq[g * 64 + l * 4 + i];
    p += v * v;
  }
  p += __shfl_xor(p, 1);
  p += __shfl_xor(p, 2);
  p += __shfl_xor(p, 4);
  p += __shfl_xor(p, 8);
  if (l == 0) scale[g] = rsqrtf(p + 1e-6f);
  __syncthreads();
  for (int c = tid; c < 1024; c += 256) {
    float s = scale[c >> 6] * ((c < 512) ? 0.125f : 1.f);  // q gets DK^-0.5
    mix[(size_t)bt * 3072 + c] = sq[c] * s;
  }
}

// ---------------- gates: g (log-decay) and beta = sigmoid(b) ----------------
__global__ __launch_bounds__(256) void gate_kernel(const float* __restrict__ qkvz,
                                                   const float* __restrict__ dt_bias,
                                                   const float* __restrict__ A_log,
                                                   float* __restrict__ gb,
                                                   float* __restrict__ beta) {
  int i = blockIdx.x * 256 + threadIdx.x;  // < 65536 = 2048*32
  int hv = i & 31;
  int bt = i >> 5;
  int hk = hv >> 2, vp = hv & 3;
  const float* row = qkvz + (size_t)bt * 5184 + 5120 + hk * 8;
  float bv = row[vp];
  float av = row[4 + vp];
  float x = av + dt_bias[hv];
  float sp = (x > 20.f) ? x : log1pf(expf(x));
  gb[i] = -expf(A_log[hv]) * sp;        // log-decay g_t (<= 0)
  beta[i] = 1.f / (1.f + expf(-bv));
}

// ---------------- chunked delta-rule precompute ----------------
__global__ __launch_bounds__(256) void precompute_kernel(
    const float* __restrict__ mix, const float* __restrict__ gbuf,
    const float* __restrict__ betab, float* __restrict__ Wbuf,
    float* __restrict__ Pbuf, float* __restrict__ Rbuf, float* __restrict__ cbuf) {
  __shared__ float Kt[64][68];   // K col-major: Kt[d][t]; later K' row-major scaled
  __shared__ float Vb[64][68];   // V row-major
  __shared__ float AM[64][68];   // A; later Q col-major
  __shared__ float Mm[64][68];   // (I+A)^{-1}
  __shared__ float Tb[16][17];
  __shared__ float cs[64], bb[64];

  const int u = blockIdx.x;
  const int chunk = u & 15, hv = (u >> 4) & 31, b = u >> 9;
  const int hk = hv >> 2;
  const int t0g = b * 1024 + chunk * 64;
  const int tid = threadIdx.x;
  const int tr = tid >> 2, q4 = tid & 3;

  {
    const float* mrow = mix + (size_t)(t0g + tr) * 3072;
#pragma unroll
    for (int e = 0; e < 4; ++e) {
      int c0 = q4 * 16 + e * 4;
      float4 kv = *(const float4*)(mrow + 512 + hk * 64 + c0);
      Kt[c0 + 0][tr] = kv.x; Kt[c0 + 1][tr] = kv.y;
      Kt[c0 + 2][tr] = kv.z; Kt[c0 + 3][tr] = kv.w;
      *(float4*)&Vb[tr][c0] = *(const float4*)(mrow + 1024 + hv * 64 + c0);
    }
  }
  if (tid < 64) {
    cs[tid] = gbuf[(size_t)(t0g + tid) * 32 + hv];
    bb[tid] = betab[(size_t)(t0g + tid) * 32 + hv];
  }
  __syncthreads();
  for (int off = 1; off < 64; off <<= 1) {
    float v = 0.f;
    if (tid < 64 && tid >= off) v = cs[tid - off];
    __syncthreads();
    if (tid < 64) cs[tid] += v;
    __syncthreads();
  }
  if (tid < 64) cbuf[(size_t)u * 64 + tid] = cs[tid];

  {
    float acc[16];
#pragma unroll
    for (int i = 0; i < 16; ++i) acc[i] = 0.f;
    for (int d = 0; d < 64; ++d) {
      float kv = Kt[d][tr];
#pragma unroll
      for (int e = 0; e < 4; ++e) {
        float4 ks = *(const float4*)&Kt[d][q4 * 16 + e * 4];
        acc[e * 4 + 0] += kv * ks.x; acc[e * 4 + 1] += kv * ks.y;
        acc[e * 4 + 2] += kv * ks.z; acc[e * 4 + 3] += kv * ks.w;
      }
    }
    float bt_ = bb[tr], ct_ = cs[tr];
#pragma unroll
    for (int j = 0; j < 16; ++j) {
      int s = q4 * 16 + j;
      AM[tr][s] = (s < tr) ? bt_ * acc[j] * __expf(ct_ - cs[s]) : 0.f;
    }
  }
  __syncthreads();

  for (int i = tid; i < 64 * 68; i += 256) (&Mm[0][0])[i] = 0.f;
  __syncthreads();
  if (tid < 64) {
    int blk = tid >> 4, j = tid & 15, base = blk * 16;
    Mm[base][base + j] = (j == 0) ? 1.f : 0.f;
    for (int r = 1; r < 16; ++r) {
      float sum = 0.f;
      for (int s = 0; s < r; ++s) sum += AM[base + r][base + s] * Mm[base + s][base + j];
      Mm[base + r][base + j] = ((r == j) ? 1.f : 0.f) - sum;
    }
  }
  __syncthreads();
  for (int d = 1; d < 4; ++d) {
    for (int j = 0; j + d < 4; ++j) {
      int i = j + d;
      int r = tid >> 4, c = tid & 15;
      float tsum = 0.f;
      for (int kb = j; kb < i; ++kb)
        for (int uu = 0; uu < 16; ++uu)
          tsum += AM[i * 16 + r][kb * 16 + uu] * Mm[kb * 16 + uu][j * 16 + c];
      Tb[r][c] = tsum;
      __syncthreads();
      float msum = 0.f;
      for (int uu = 0; uu < 16; ++uu)
        msum += Mm[i * 16 + r][i * 16 + uu] * Tb[uu][c];
      __syncthreads();
      Mm[i * 16 + r][j * 16 + c] = -msum;
      __syncthreads();
    }
  }

  {
    const float* mrow = mix + (size_t)(t0g + tr) * 3072 + hk * 64;
#pragma unroll
    for (int e = 0; e < 4; ++e) {
      int c0 = q4 * 16 + e * 4;
      float4 qv = *(const float4*)(mrow + c0);
      AM[c0 + 0][tr] = qv.x; AM[c0 + 1][tr] = qv.y;
      AM[c0 + 2][tr] = qv.z; AM[c0 + 3][tr] = qv.w;
    }
  }
  __syncthreads();

  {
    float acc[16];
#pragma unroll
    for (int i = 0; i < 16; ++i) acc[i] = 0.f;
    for (int d = 0; d < 64; ++d) {
      float qv = AM[d][tr];
#pragma unroll
      for (int e = 0; e < 4; ++e) {
        float4 ks = *(const float4*)&Kt[d][q4 * 16 + e * 4];
        acc[e * 4 + 0] += qv * ks.x; acc[e * 4 + 1] += qv * ks.y;
        acc[e * 4 + 2] += qv * ks.z; acc[e * 4 + 3] += qv * ks.w;
      }
    }
    float ct_ = cs[tr];
#pragma unroll
    for (int e = 0; e < 4; ++e) {
      int s0 = q4 * 16 + e * 4;
      float4 pv;
      pv.x = (s0 + 0 <= tr) ? acc[e * 4 + 0] * __expf(ct_ - cs[s0 + 0]) : 0.f;
      pv.y = (s0 + 1 <= tr) ? acc[e * 4 + 1] * __expf(ct_ - cs[s0 + 1]) : 0.f;
      pv.z = (s0 + 2 <= tr) ? acc[e * 4 + 2] * __expf(ct_ - cs[s0 + 2]) : 0.f;
      pv.w = (s0 + 3 <= tr) ? acc[e * 4 + 3] * __expf(ct_ - cs[s0 + 3]) : 0.f;
      *(float4*)&Pbuf[(size_t)u * 4096 + tr * 64 + s0] = pv;
    }
  }
  __syncthreads();

  {
    float vals[16];
#pragma unroll
    for (int j = 0; j < 16; ++j) vals[j] = Kt[q4 * 16 + j][tr];
    float sc = bb[tr] * __expf(cs[tr]);
    __syncthreads();
#pragma unroll
    for (int j = 0; j < 16; ++j) Kt[tr][q4 * 16 + j] = vals[j] * sc;
  }
  __syncthreads();

  {
    float acc[16];
#pragma unroll
    for (int i = 0; i < 16; ++i) acc[i] = 0.f;
    for (int s = 0; s < 64; ++s) {
      float m = Mm[tr][s];
#pragma unroll
      for (int e = 0; e < 4; ++e) {
        float4 kk = *(const float4*)&Kt[s][q4 * 16 + e * 4];
        acc[e * 4 + 0] += m * kk.x; acc[e * 4 + 1] += m * kk.y;
        acc[e * 4 + 2] += m * kk.z; acc[e * 4 + 3] += m * kk.w;
      }
    }
#pragma unroll
    for (int e = 0; e < 4; ++e) {
      float4 wv = {acc[e * 4 + 0], acc[e * 4 + 1], acc[e * 4 + 2], acc[e * 4 + 3]};
      *(float4*)&Wbuf[(size_t)u * 4096 + tr * 64 + q4 * 16 + e * 4] = wv;
    }
  }
  {
    float acc[16];
#pragma unroll
    for (int i = 0; i < 16; ++i) acc[i] = 0.f;
    for (int s = 0; s < 64; ++s) {
      float m = Mm[tr][s] * bb[s];
#pragma unroll
      for (int e = 0; e < 4; ++e) {
        float4 vv = *(const float4*)&Vb[s][q4 * 16 + e * 4];
        acc[e * 4 + 0] += m * vv.x; acc[e * 4 + 1] += m * vv.y;
        acc[e * 4 + 2] += m * vv.z; acc[e * 4 + 3] += m * vv.w;
      }
    }
#pragma unroll
    for (int e = 0; e < 4; ++e) {
      float4 rv = {acc[e * 4 + 0], acc[e * 4 + 1], acc[e * 4 + 2], acc[e * 4 + 3]};
      *(float4*)&Rbuf[(size_t)u * 4096 + tr * 64 + q4 * 16 + e * 4] = rv;
    }
  }
}

// ---------------- chunked serial scan ----------------
// 512 threads = 8 waves.  Thread = (tr 0..63, q8 0..7); owns 2 cols {2q8, 2q8+1}
// of the 64x16 vs-slice.  All per-chunk operands stored so inner loops read
// contiguous float4 rows:
//   Wb[t][kd], Pb[t][s], Qh[t][kd] (pre-scaled by exp(c_t)),
//   Kt[kd][t]  (transposed + pre-scaled by exp(c63-c_t)),
//   St[v][kd]  (S^T state), Dt[v][t] (D^T workspace).
__global__ __launch_bounds__(512) void chunk_scan_kernel(
    const float* __restrict__ mix, const float* __restrict__ Wbuf,
    const float* __restrict__ Pbuf, const float* __restrict__ Rbuf,
    const float* __restrict__ cbuf, float* __restrict__ o) {
  __shared__ float Wb[64][68], Pb[64][68], Qh[64][68], Kt[64][68];
  __shared__ float St[16][68], Dt[16][68];
  __shared__ float cs[64];

  const int bid = blockIdx.x;
  const int vs = bid & 3, hv = (bid >> 2) & 31, b = bid >> 7;
  const int hk = hv >> 2;
  const int bh = b * 32 + hv;
  const int ubase = bh * 16;
  const int tid = threadIdx.x;
  const int tr = tid >> 3, q8 = tid & 7;
  const int c0 = q8 * 2, c1 = q8 * 2 + 1;

  // zero S^T state
  for (int i = tid; i < 16 * 68; i += 512) (&St[0][0])[i] = 0.f;

  float4 WN[2], PN[2], KN[2], QN[2];
  float2 RN;
  float cN = 0.f;
  float e63c = 1.f;

#define ISSUE_LOADS(c)                                                          \
  {                                                                             \
    size_t uu = (size_t)(ubase + (c));                                          \
    _Pragma("unroll") for (int i = 0; i < 2; ++i) {                             \
      WN[i] = ((const float4*)(Wbuf + uu * 4096))[tid + 512 * i];               \
      PN[i] = ((const float4*)(Pbuf + uu * 4096))[tid + 512 * i];               \
    }                                                                           \
    const float* mrow = mix + (size_t)(b * 1024 + (c) * 64 + tr) * 3072;        \
    _Pragma("unroll") for (int e = 0; e < 2; ++e) {                             \
      KN[e] = *(const float4*)(mrow + 512 + hk * 64 + q8 * 8 + e * 4);          \
      QN[e] = *(const float4*)(mrow + hk * 64 + q8 * 8 + e * 4);                \
    }                                                                           \
    RN = *(const float2*)(Rbuf + uu * 4096 + tr * 64 + vs * 16 + q8 * 2);       \
    if (tid < 64) cN = cbuf[uu * 64 + tid];                                     \
  }

  // stage W,P,cs (pre-barrier); then scale+write Qh,Kt (post-barrier).
  // e63c (register) carries exp(cs[63]) of the staged chunk into its S-update.
#define COMMIT()                                                                \
  {                                                                             \
    _Pragma("unroll") for (int i = 0; i < 2; ++i) {                             \
      int flat = (tid + 512 * i) * 4;                                           \
      int rr = flat >> 6, cc = flat & 63;                                       \
      *(float4*)&Wb[rr][cc] = WN[i];                                            \
      *(float4*)&Pb[rr][cc] = PN[i];                                            \
    }                                                                           \
    if (tid < 64) cs[tid] = cN;                                                 \
    __syncthreads();                                                            \
    float csv = cs[tr], cs63 = cs[63];                                          \
    float sQv = __expf(csv), sKv = __expf(cs63 - csv);                          \
    e63c = __expf(cs63);                                                        \
    float4 qa, qb;                                                              \
    qa.x = QN[0].x * sQv; qa.y = QN[0].y * sQv;                                 \
    qa.z = QN[0].z * sQv; qa.w = QN[0].w * sQv;                                 \
    qb.x = QN[1].x * sQv; qb.y = QN[1].y * sQv;                                 \
    qb.z = QN[1].z * sQv; qb.w = QN[1].w * sQv;                                 \
    *(float4*)&Qh[tr][q8 * 8] = qa;                                             \
    *(float4*)&Qh[tr][q8 * 8 + 4] = qb;                                         \
    Kt[q8 * 8 + 0][tr] = KN[0].x * sKv;                                         \
    Kt[q8 * 8 + 1][tr] = KN[0].y * sKv;                                         \
    Kt[q8 * 8 + 2][tr] = KN[0].z * sKv;                                         \
    Kt[q8 * 8 + 3][tr] = KN[0].w * sKv;                                         \
    Kt[q8 * 8 + 4][tr] = KN[1].x * sKv;                                         \
    Kt[q8 * 8 + 5][tr] = KN[1].y * sKv;                                         \
    Kt[q8 * 8 + 6][tr] = KN[1].z * sKv;                                         \
    Kt[q8 * 8 + 7][tr] = KN[1].w * sKv;                                         \
  }

  ISSUE_LOADS(0);
  COMMIT();
  float2 Rv = RN;

  for (int c = 0; c < 16; ++c) {
    if (c < 15) ISSUE_LOADS(c + 1);
    // ---- D[t][v] = R - W @ S : acc over kd, contiguous in Wb row / St row ----
    float2 acc = Rv;
#pragma unroll 4
    for (int k = 0; k < 64; k += 4) {
      float4 w4 = *(const float4*)&Wb[tr][k];
      float4 sa = *(const float4*)&St[c0][k];
      float4 sb = *(const float4*)&St[c1][k];
      acc.x -= w4.x * sa.x + w4.y * sa.y + w4.z * sa.z + w4.w * sa.w;
      acc.y -= w4.x * sb.x + w4.y * sb.y + w4.z * sb.z + w4.w * sb.w;
    }
    Dt[c0][tr] = acc.x;
    Dt[c1][tr] = acc.y;
    __syncthreads();
    // ---- O[t][v] = P @ D + Qh @ S ----
    {
      float2 ao = {0.f, 0.f};
#pragma unroll 4
      for (int i = 0; i < 64; i += 4) {
        float4 p4 = *(const float4*)&Pb[tr][i];
        float4 q4 = *(const float4*)&Qh[tr][i];
        float4 da = *(const float4*)&Dt[c0][i];
        float4 db = *(const float4*)&Dt[c1][i];
        float4 sa = *(const float4*)&St[c0][i];
        float4 sb = *(const float4*)&St[c1][i];
        ao.x += p4.x * da.x + p4.y * da.y + p4.z * da.z + p4.w * da.w
              + q4.x * sa.x + q4.y * sa.y + q4.z * sa.z + q4.w * sa.w;
        ao.y += p4.x * db.x + p4.y * db.y + p4.z * db.z + p4.w * db.w
              + q4.x * sb.x + q4.y * sb.y + q4.z * sb.z + q4.w * sb.w;
      }
      *(float2*)&o[((size_t)(bh * 4 + vs) * 1024 + c * 64 + tr) * 16 + q8 * 2] = ao;
    }
    __syncthreads();
    // ---- S^T[v][kd] = e63*S^T + (Kt @ D^T-style row dot) ----
    {
      float sx = St[c0][tr] * e63c;
      float sy = St[c1][tr] * e63c;
#pragma unroll 4
      for (int t = 0; t < 64; t += 4) {
        float4 k4 = *(const float4*)&Kt[tr][t];
        float4 da = *(const float4*)&Dt[c0][t];
        float4 db = *(const float4*)&Dt[c1][t];
        sx += k4.x * da.x + k4.y * da.y + k4.z * da.z + k4.w * da.w;
        sy += k4.x * db.x + k4.y * db.y + k4.z * db.z + k4.w * db.w;
      }
      St[c0][tr] = sx;
      St[c1][tr] = sy;
    }
    if (c < 15) {
      COMMIT();   // internal barrier also orders St/Dt reuse across chunks
      Rv = RN;
    }
  }
#undef ISSUE_LOADS
#undef COMMIT
}

// ---------------- rmsnorm * norm_w * silu(z), -> bf16 ----------------
// reads o in block-local layout o[(bh*4+vs)][t][16]; writes on[bt][hv*64+d] (standard)
__global__ __launch_bounds__(256) void rms_gate_kernel(const float* __restrict__ o,
                                                       const float* __restrict__ qkvz,
                                                       const float* __restrict__ norm_w,
                                                       short* __restrict__ on) {
  int bid = blockIdx.x;            // (bh)*256 + tgroup
  int bh = bid >> 8;               // b*32+hv
  int tg = bid & 255;
  int b = bh >> 5, hv = bh & 31;
  int t = tg * 4 + (threadIdx.x >> 6);
  int d = threadIdx.x & 63;
  int bt = b * 1024 + t;
  int hk = hv >> 2, vp = hv & 3;
  float x = o[((size_t)(bh * 4 + (d >> 4)) * 1024 + t) * 16 + (d & 15)];
  float ss = x * x;
  ss += __shfl_xor(ss, 1);
  ss += __shfl_xor(ss, 2);
  ss += __shfl_xor(ss, 4);
  ss += __shfl_xor(ss, 8);
  ss += __shfl_xor(ss, 16);
  ss += __shfl_xor(ss, 32);
  float sc = rsqrtf(ss * (1.f / 64.f) + 1e-5f);
  float z = qkvz[(size_t)bt * 5184 + hk * 640 + 384 + vp * 64 + d];
  float val = x * sc * norm_w[d] * (z / (1.f + __expf(-z)));
  on[((size_t)bt * 32 + hv) * 64 + d] = f2bf(val);
}

// ---------------- launch ----------------
extern "C" void kernel_launch(void* const* d_in, const int* in_sizes, int n_in,
                              void* d_out, int out_size, void* d_ws, size_t ws_size,
                              hipStream_t stream) {
  const float* hidden = (const float*)d_in[0];
  const float* W_qkvz = (const float*)d_in[1];
  const float* W_ba = (const float*)d_in[2];
  const float* conv_w = (const float*)d_in[3];
  const float* dt_bias = (const float*)d_in[4];
  const float* A_log = (const float*)d_in[5];
  const float* norm_w = (const float*)d_in[6];
  const float* W_out = (const float*)d_in[7];
  float* out = (float*)d_out;

  char* ws = (char*)d_ws;
  short* A_bf = (short*)(ws + 0);                // 16,777,216
  short* Wt1 = (short*)(ws + 16777216);          // 42,991,616  [5248][4096] (pad)
  short* Wt2 = (short*)(ws + 59768832);          // 16,777,216  [4096][2048]
  float* qkvz = (float*)(ws + 76546048);         // 42,467,328  [2048][5184]
  float* mix = (float*)(ws + 119013376);         // 25,165,824  [2048][3072]
  float* gbuf = (float*)(ws + 144179200);        //    262,144  [2048][32]
  float* beta = (float*)(ws + 144441344);        //    262,144
  float* o = (float*)(ws + 144703488);           // 16,777,216  [256][1024][16] block-local
  short* on = (short*)(ws + 161480704);          //  8,388,608  [2048][2048]
  float* Wbuf = (float*)(ws + 169869312);        // 16,777,216  [1024][64][64]
  float* Pbuf = (float*)(ws + 186646528);        // 16,777,216
  float* Rbuf = (float*)(ws + 203423744);        // 16,777,216
  float* cbuf = (float*)(ws + 220200960);        //    262,144  [1024][64]

  to_bf16_kernel<<<8192, 256, 0, stream>>>(hidden, A_bf);
  transpose_w1<<<dim3(164, 128), 256, 0, stream>>>(W_qkvz, W_ba, Wt1);
  transpose_w2<<<dim3(128, 64), 256, 0, stream>>>(W_out, Wt2);
  // gemm256: N guarded at 5184; staging reads past row 5248 hit ws scratch (safe,
  // values discarded by the guard).
  gemm256<true><<<dim3(8, 21), 512, 0, stream>>>(A_bf, Wt1, qkvz, 2048, 5184, 4096);
  conv_kernel<<<2048, 256, 0, stream>>>(qkvz, conv_w, mix);
  gate_kernel<<<256, 256, 0, stream>>>(qkvz, dt_bias, A_log, gbuf, beta);
  precompute_kernel<<<1024, 256, 0, stream>>>(mix, gbuf, beta, Wbuf, Pbuf, Rbuf, cbuf);
  chunk_scan_kernel<<<256, 512, 0, stream>>>(mix, Wbuf, Pbuf, Rbuf, cbuf, o);
  rms_gate_kernel<<<16384, 256, 0, stream>>>(o, qkvz, norm_w, on);
  gemm128<false><<<dim3(16, 32), 256, 0, stream>>>(on, Wt2, out, 2048, 4096, 2048);
}

// Round 4
// 562.571 us; speedup vs baseline: 1.1826x; 1.0660x over previous
//
#include <hip/hip_runtime.h>
#include <hip/hip_bf16.h>
#include <cstdint>
#include <cstddef>

// ---------------- constants ----------------
// B=2 T=1024 H=4096 HK=8 HV=32 DK=64 DV=64 VPK=4
// GEMM1: A[2048][4096] * Wt1[5248(pad 5184)][4096]^T -> qkvz[2048][5184]
// GEMM2: on[2048][2048] * Wt2[4096][2048]^T -> out[2048][4096] (fp32)
// Both GEMMs: gemm128p (pipelined 128x128, 3-buffer, counted vmcnt, XCD swizzle)
// Scan: chunked delta rule, chunk C=64, units = b(2) x hv(32) x chunk(16)

typedef __attribute__((ext_vector_type(8))) short short8;
typedef __attribute__((ext_vector_type(4))) float f32x4;

__device__ __forceinline__ short f2bf(float f) {
  union { float f; unsigned u; } x; x.f = f;
  unsigned r = x.u + 0x7fffu + ((x.u >> 16) & 1u);
  return (short)(r >> 16);
}

__device__ __forceinline__ void gl_lds16(const short* g, short* l) {
  __builtin_amdgcn_global_load_lds(
      (const __attribute__((address_space(1))) void*)g,
      (__attribute__((address_space(3))) void*)l, 16, 0, 0);
}

// ---------------- elementwise fp32 -> bf16 ----------------
__global__ __launch_bounds__(256) void to_bf16_kernel(const float* __restrict__ x,
                                                      short* __restrict__ y) {
  int i = blockIdx.x * 256 + threadIdx.x;   // one float4 per thread
  float4 v = ((const float4*)x)[i];
  ushort4 r;
  r.x = (unsigned short)f2bf(v.x);
  r.y = (unsigned short)f2bf(v.y);
  r.z = (unsigned short)f2bf(v.z);
  r.w = (unsigned short)f2bf(v.w);
  ((ushort4*)y)[i] = r;
}

// ---------------- transpose+convert W_qkvz|W_ba -> Wt1[n][k], pad to 5248 ----------------
__global__ __launch_bounds__(256) void transpose_w1(const float* __restrict__ Wq,
                                                    const float* __restrict__ Wba,
                                                    short* __restrict__ Wt) {
  __shared__ float tile[32][33];
  int n0 = blockIdx.x * 32;  // < 5248
  int k0 = blockIdx.y * 32;  // < 4096
  int t = threadIdx.x;
  int r = t >> 5;    // 0..7
  int c = t & 31;
#pragma unroll
  for (int i = 0; i < 4; ++i) {
    int kl = r + i * 8;
    int n = n0 + c;
    float v = 0.f;
    if (n < 5120) v = Wq[(size_t)(k0 + kl) * 5120 + n];
    else if (n < 5184) v = Wba[(size_t)(k0 + kl) * 64 + (n - 5120)];
    tile[kl][c] = v;
  }
  __syncthreads();
#pragma unroll
  for (int i = 0; i < 4; ++i) {
    int nl = r + i * 8;
    int kl = c;
    Wt[(size_t)(n0 + nl) * 4096 + k0 + kl] = f2bf(tile[kl][nl]);
  }
}

// ---------------- transpose+convert W_out -> Wt2[n][k] ----------------
__global__ __launch_bounds__(256) void transpose_w2(const float* __restrict__ W,
                                                    short* __restrict__ Wt) {
  __shared__ float tile[32][33];
  int n0 = blockIdx.x * 32;  // < 4096
  int k0 = blockIdx.y * 32;  // < 2048
  int t = threadIdx.x;
  int r = t >> 5;
  int c = t & 31;
#pragma unroll
  for (int i = 0; i < 4; ++i) {
    int kl = r + i * 8;
    tile[kl][c] = W[(size_t)(k0 + kl) * 4096 + n0 + c];
  }
  __syncthreads();
#pragma unroll
  for (int i = 0; i < 4; ++i) {
    int nl = r + i * 8;
    int kl = c;
    Wt[(size_t)(n0 + nl) * 2048 + k0 + kl] = f2bf(tile[kl][nl]);
  }
}

// ---------------- 128x128 pipelined bf16 MFMA GEMM (3-stage, counted vmcnt) ----
// BM=BN=128, BK=32, 256 threads = 4 waves (2M x 2N), per-wave C = 64x64.
// LDS: 3 buffers x (A 8KB + B 8KB) = 48 KiB -> 3 blocks/CU co-resident (the MLP
// lever: per-block staging is ~13.6 B/cyc, scales with resident blocks).
// Staging of kt+2 writes buffer (kt+2)%3 whose last reads finished a barrier
// ago -> race-free with loads in flight (vmcnt(4), never 0 in steady state).
// LDS layout: 16B slot(row,s) -> phys slot rp*8 + (((row&1)*4+s)^(rp&7)),
// rp=row>>1 (measured: 0 bank conflicts).  global_load_lds dest stays LINEAR;
// the permutation is applied to the per-lane global source address.
// Grid is 1-D, XCD-swizzled: swz=(bid%8)*(nwg/8)+bid/8 (nwg%8==0, bijective);
// tile = (swz%MT, swz/MT) -> each XCD owns a contiguous column-major chunk.
template <bool GUARD_N>
__global__ __launch_bounds__(256) void gemm128p(const short* __restrict__ A,
                                                const short* __restrict__ Bt,
                                                float* __restrict__ C,
                                                int N, int K, int MT) {
  __shared__ __align__(16) short As[3 * 4096];
  __shared__ __align__(16) short Bs[3 * 4096];
  const int tid = threadIdx.x;
  const int w = tid >> 6, lane = tid & 63;
  const int wm = w >> 1, wn = w & 1;

  const int nwg = gridDim.x;
  const int bid = blockIdx.x;
  const int swz = (bid & 7) * (nwg >> 3) + (bid >> 3);
  const int m0 = (swz % MT) * 128;
  const int n0 = (swz / MT) * 128;

  // staging: phys slot p = round*256 + w*64 + lane  ->  (row, s)
  const int p0 = w * 64 + lane;
  const int rp0 = p0 >> 3, q0 = p0 & 7;
  const int mm0 = q0 ^ (rp0 & 7);
  const int srow = rp0 * 2 + (mm0 >> 2);     // 0..63 (round1 = +64)
  const int scol = (mm0 & 3) << 3;           // elem offset 0/8/16/24
  const short* Ag = A + (size_t)(m0 + srow) * K + scol;
  const short* Bg = Bt + (size_t)(n0 + srow) * K + scol;
  const size_t rstep = (size_t)64 * K;

  // fragment read offsets (shorts): row = frag base + (lane&15), s = lane>>4
  const int fr = lane & 15;
  const int s = lane >> 4;
  int aoff[4], boff[4];
#pragma unroll
  for (int i = 0; i < 4; ++i) {
    int row = wm * 64 + i * 16 + fr;
    int rp = row >> 1;
    int q = (((row & 1) << 2) | s) ^ (rp & 7);
    aoff[i] = (rp * 8 + q) * 8;
  }
#pragma unroll
  for (int j = 0; j < 4; ++j) {
    int row = wn * 64 + j * 16 + fr;
    int rp = row >> 1;
    int q = (((row & 1) << 2) | s) ^ (rp & 7);
    boff[j] = (rp * 8 + q) * 8;
  }

  f32x4 acc[4][4];
#pragma unroll
  for (int i = 0; i < 4; ++i)
#pragma unroll
    for (int j = 0; j < 4; ++j) acc[i][j] = (f32x4){0.f, 0.f, 0.f, 0.f};

  const int NKT = K >> 5;

#define STAGE_A(kt, bb)                                                \
  { const short* g = Ag + (size_t)(kt) * 32;                           \
    gl_lds16(g,         &As[(bb) * 4096 + w * 512]);                   \
    gl_lds16(g + rstep, &As[(bb) * 4096 + 2048 + w * 512]); }
#define STAGE_B(kt, bb)                                                \
  { const short* g = Bg + (size_t)(kt) * 32;                           \
    gl_lds16(g,         &Bs[(bb) * 4096 + w * 512]);                   \
    gl_lds16(g + rstep, &Bs[(bb) * 4096 + 2048 + w * 512]); }

  // prologue: stage kt0 -> buf0, kt1 -> buf1; wait kt0 resident (4 in flight ok)
  STAGE_A(0, 0); STAGE_B(0, 0);
  STAGE_A(1, 1); STAGE_B(1, 1);
  asm volatile("s_waitcnt vmcnt(4)" ::: "memory");
  __builtin_amdgcn_s_barrier();
  __builtin_amdgcn_sched_barrier(0);

  int bi = 0;
  for (int kt = 0; kt < NKT; ++kt) {
    int bi2 = bi - 1; if (bi2 < 0) bi2 = 2;   // (kt+2)%3
    const short* Ab = &As[bi * 4096];
    const short* Bb = &Bs[bi * 4096];
    short8 af[2], bf[4];
    // ---- phase 1: frags(m0-1, n0-3) + stage A(kt+2) ----
#pragma unroll
    for (int i = 0; i < 2; ++i) af[i] = *(const short8*)&Ab[aoff[i]];
#pragma unroll
    for (int j = 0; j < 4; ++j) bf[j] = *(const short8*)&Bb[boff[j]];
    if (kt + 2 < NKT) STAGE_A(kt + 2, bi2);
    __builtin_amdgcn_s_barrier();
    asm volatile("s_waitcnt lgkmcnt(0)" ::: "memory");
    __builtin_amdgcn_sched_barrier(0);
    __builtin_amdgcn_s_setprio(1);
#pragma unroll
    for (int i = 0; i < 2; ++i)
#pragma unroll
      for (int j = 0; j < 4; ++j)
        acc[i][j] = __builtin_amdgcn_mfma_f32_16x16x32_bf16(af[i], bf[j], acc[i][j], 0, 0, 0);
    __builtin_amdgcn_s_setprio(0);
    __builtin_amdgcn_sched_barrier(0);
    // ---- phase 2: frags(m2-3) + stage B(kt+2); counted vmcnt ----
#pragma unroll
    for (int i = 0; i < 2; ++i) af[i] = *(const short8*)&Ab[aoff[i + 2]];
    if (kt + 2 < NKT) STAGE_B(kt + 2, bi2);
    if (kt < NKT - 2) { asm volatile("s_waitcnt vmcnt(4)" ::: "memory"); }
    else              { asm volatile("s_waitcnt vmcnt(0)" ::: "memory"); }
    __builtin_amdgcn_s_barrier();
    asm volatile("s_waitcnt lgkmcnt(0)" ::: "memory");
    __builtin_amdgcn_sched_barrier(0);
    __builtin_amdgcn_s_setprio(1);
#pragma unroll
    for (int i = 0; i < 2; ++i)
#pragma unroll
      for (int j = 0; j < 4; ++j)
        acc[i + 2][j] = __builtin_amdgcn_mfma_f32_16x16x32_bf16(af[i], bf[j], acc[i + 2][j], 0, 0, 0);
    __builtin_amdgcn_s_setprio(0);
    __builtin_amdgcn_sched_barrier(0);
    __builtin_amdgcn_s_barrier();   // trailing: makes next-iter staging into bi safe
    ++bi; if (bi == 3) bi = 0;
  }
#undef STAGE_A
#undef STAGE_B

  // C/D layout: col = lane&15, row = (lane>>4)*4 + r
  const int rbase = (lane >> 4) << 2;
#pragma unroll
  for (int i = 0; i < 4; ++i) {
#pragma unroll
    for (int j = 0; j < 4; ++j) {
      int col = n0 + wn * 64 + j * 16 + fr;
      if (GUARD_N && col >= N) continue;
      int row = m0 + wm * 64 + i * 16 + rbase;
#pragma unroll
      for (int r = 0; r < 4; ++r)
        C[(size_t)(row + r) * N + col] = acc[i][j][r];
    }
  }
}

// ---------------- conv(4-tap causal) + silu + l2norm(q,k) ----------------
__global__ __launch_bounds__(256) void conv_kernel(const float* __restrict__ qkvz,
                                                   const float* __restrict__ conv_w,
                                                   float* __restrict__ mix) {
  __shared__ float sq[1024];
  __shared__ float scale[16];
  int bt = blockIdx.x;       // b*1024 + t
  int t = bt & 1023;
  int tid = threadIdx.x;
  for (int c = tid; c < 3072; c += 256) {
    int col;
    if (c < 512) {
      col = (c >> 6) * 640 + (c & 63);
    } else if (c < 1024) {
      int c2 = c - 512;
      col = (c2 >> 6) * 640 + 64 + (c2 & 63);
    } else {
      int c3 = c - 1024;
      int hv = c3 >> 6;
      col = (hv >> 2) * 640 + 128 + (hv & 3) * 64 + (c3 & 63);
    }
    float acc = 0.f;
#pragma unroll
    for (int j = 0; j < 4; ++j) {
      int tt = t - 3 + j;
      if (tt >= 0) acc += qkvz[(size_t)(bt - 3 + j) * 5184 + col] * conv_w[c * 4 + j];
    }
    float sv = acc / (1.f + __expf(-acc));  // silu
    if (c < 1024)
      sq[c] = sv;
    else
      mix[(size_t)bt * 3072 + c] = sv;
  }
  __syncthreads();
  int g = tid >> 4, l = tid & 15;
  float p = 0.f;
#pragma unroll
  for (int i = 0; i < 4; ++i) {
    float v = sq[g * 64 + l * 4 + i];
    p += v * v;
  }
  p += __shfl_xor(p, 1);
  p += __shfl_xor(p, 2);
  p += __shfl_xor(p, 4);
  p += __shfl_xor(p, 8);
  if (l == 0) scale[g] = rsqrtf(p + 1e-6f);
  __syncthreads();
  for (int c = tid; c < 1024; c += 256) {
    float s = scale[c >> 6] * ((c < 512) ? 0.125f : 1.f);  // q gets DK^-0.5
    mix[(size_t)bt * 3072 + c] = sq[c] * s;
  }
}

// ---------------- gates: g (log-decay) and beta = sigmoid(b) ----------------
__global__ __launch_bounds__(256) void gate_kernel(const float* __restrict__ qkvz,
                                                   const float* __restrict__ dt_bias,
                                                   const float* __restrict__ A_log,
                                                   float* __restrict__ gb,
                                                   float* __restrict__ beta) {
  int i = blockIdx.x * 256 + threadIdx.x;  // < 65536 = 2048*32
  int hv = i & 31;
  int bt = i >> 5;
  int hk = hv >> 2, vp = hv & 3;
  const float* row = qkvz + (size_t)bt * 5184 + 5120 + hk * 8;
  float bv = row[vp];
  float av = row[4 + vp];
  float x = av + dt_bias[hv];
  float sp = (x > 20.f) ? x : log1pf(expf(x));
  gb[i] = -expf(A_log[hv]) * sp;        // log-decay g_t (<= 0)
  beta[i] = 1.f / (1.f + expf(-bv));
}

// ---------------- chunked delta-rule precompute ----------------
__global__ __launch_bounds__(256) void precompute_kernel(
    const float* __restrict__ mix, const float* __restrict__ gbuf,
    const float* __restrict__ betab, float* __restrict__ Wbuf,
    float* __restrict__ Pbuf, float* __restrict__ Rbuf, float* __restrict__ cbuf) {
  __shared__ float Kt[64][68];   // K col-major: Kt[d][t]; later K' row-major scaled
  __shared__ float Vb[64][68];   // V row-major
  __shared__ float AM[64][68];   // A; later Q col-major
  __shared__ float Mm[64][68];   // (I+A)^{-1}
  __shared__ float Tb[16][17];
  __shared__ float cs[64], bb[64];

  const int u = blockIdx.x;
  const int chunk = u & 15, hv = (u >> 4) & 31, b = u >> 9;
  const int hk = hv >> 2;
  const int t0g = b * 1024 + chunk * 64;
  const int tid = threadIdx.x;
  const int tr = tid >> 2, q4 = tid & 3;

  {
    const float* mrow = mix + (size_t)(t0g + tr) * 3072;
#pragma unroll
    for (int e = 0; e < 4; ++e) {
      int c0 = q4 * 16 + e * 4;
      float4 kv = *(const float4*)(mrow + 512 + hk * 64 + c0);
      Kt[c0 + 0][tr] = kv.x; Kt[c0 + 1][tr] = kv.y;
      Kt[c0 + 2][tr] = kv.z; Kt[c0 + 3][tr] = kv.w;
      *(float4*)&Vb[tr][c0] = *(const float4*)(mrow + 1024 + hv * 64 + c0);
    }
  }
  if (tid < 64) {
    cs[tid] = gbuf[(size_t)(t0g + tid) * 32 + hv];
    bb[tid] = betab[(size_t)(t0g + tid) * 32 + hv];
  }
  __syncthreads();
  for (int off = 1; off < 64; off <<= 1) {
    float v = 0.f;
    if (tid < 64 && tid >= off) v = cs[tid - off];
    __syncthreads();
    if (tid < 64) cs[tid] += v;
    __syncthreads();
  }
  if (tid < 64) cbuf[(size_t)u * 64 + tid] = cs[tid];

  {
    float acc[16];
#pragma unroll
    for (int i = 0; i < 16; ++i) acc[i] = 0.f;
    for (int d = 0; d < 64; ++d) {
      float kv = Kt[d][tr];
#pragma unroll
      for (int e = 0; e < 4; ++e) {
        float4 ks = *(const float4*)&Kt[d][q4 * 16 + e * 4];
        acc[e * 4 + 0] += kv * ks.x; acc[e * 4 + 1] += kv * ks.y;
        acc[e * 4 + 2] += kv * ks.z; acc[e * 4 + 3] += kv * ks.w;
      }
    }
    float bt_ = bb[tr], ct_ = cs[tr];
#pragma unroll
    for (int j = 0; j < 16; ++j) {
      int s = q4 * 16 + j;
      AM[tr][s] = (s < tr) ? bt_ * acc[j] * __expf(ct_ - cs[s]) : 0.f;
    }
  }
  __syncthreads();

  for (int i = tid; i < 64 * 68; i += 256) (&Mm[0][0])[i] = 0.f;
  __syncthreads();
  if (tid < 64) {
    int blk = tid >> 4, j = tid & 15, base = blk * 16;
    Mm[base][base + j] = (j == 0) ? 1.f : 0.f;
    for (int r = 1; r < 16; ++r) {
      float sum = 0.f;
      for (int s = 0; s < r; ++s) sum += AM[base + r][base + s] * Mm[base + s][base + j];
      Mm[base + r][base + j] = ((r == j) ? 1.f : 0.f) - sum;
    }
  }
  __syncthreads();
  for (int d = 1; d < 4; ++d) {
    for (int j = 0; j + d < 4; ++j) {
      int i = j + d;
      int r = tid >> 4, c = tid & 15;
      float tsum = 0.f;
      for (int kb = j; kb < i; ++kb)
        for (int uu = 0; uu < 16; ++uu)
          tsum += AM[i * 16 + r][kb * 16 + uu] * Mm[kb * 16 + uu][j * 16 + c];
      Tb[r][c] = tsum;
      __syncthreads();
      float msum = 0.f;
      for (int uu = 0; uu < 16; ++uu)
        msum += Mm[i * 16 + r][i * 16 + uu] * Tb[uu][c];
      __syncthreads();
      Mm[i * 16 + r][j * 16 + c] = -msum;
      __syncthreads();
    }
  }

  {
    const float* mrow = mix + (size_t)(t0g + tr) * 3072 + hk * 64;
#pragma unroll
    for (int e = 0; e < 4; ++e) {
      int c0 = q4 * 16 + e * 4;
      float4 qv = *(const float4*)(mrow + c0);
      AM[c0 + 0][tr] = qv.x; AM[c0 + 1][tr] = qv.y;
      AM[c0 + 2][tr] = qv.z; AM[c0 + 3][tr] = qv.w;
    }
  }
  __syncthreads();

  {
    float acc[16];
#pragma unroll
    for (int i = 0; i < 16; ++i) acc[i] = 0.f;
    for (int d = 0; d < 64; ++d) {
      float qv = AM[d][tr];
#pragma unroll
      for (int e = 0; e < 4; ++e) {
        float4 ks = *(const float4*)&Kt[d][q4 * 16 + e * 4];
        acc[e * 4 + 0] += qv * ks.x; acc[e * 4 + 1] += qv * ks.y;
        acc[e * 4 + 2] += qv * ks.z; acc[e * 4 + 3] += qv * ks.w;
      }
    }
    float ct_ = cs[tr];
#pragma unroll
    for (int e = 0; e < 4; ++e) {
      int s0 = q4 * 16 + e * 4;
      float4 pv;
      pv.x = (s0 + 0 <= tr) ? acc[e * 4 + 0] * __expf(ct_ - cs[s0 + 0]) : 0.f;
      pv.y = (s0 + 1 <= tr) ? acc[e * 4 + 1] * __expf(ct_ - cs[s0 + 1]) : 0.f;
      pv.z = (s0 + 2 <= tr) ? acc[e * 4 + 2] * __expf(ct_ - cs[s0 + 2]) : 0.f;
      pv.w = (s0 + 3 <= tr) ? acc[e * 4 + 3] * __expf(ct_ - cs[s0 + 3]) : 0.f;
      *(float4*)&Pbuf[(size_t)u * 4096 + tr * 64 + s0] = pv;
    }
  }
  __syncthreads();

  {
    float vals[16];
#pragma unroll
    for (int j = 0; j < 16; ++j) vals[j] = Kt[q4 * 16 + j][tr];
    float sc = bb[tr] * __expf(cs[tr]);
    __syncthreads();
#pragma unroll
    for (int j = 0; j < 16; ++j) Kt[tr][q4 * 16 + j] = vals[j] * sc;
  }
  __syncthreads();

  {
    float acc[16];
#pragma unroll
    for (int i = 0; i < 16; ++i) acc[i] = 0.f;
    for (int s = 0; s < 64; ++s) {
      float m = Mm[tr][s];
#pragma unroll
      for (int e = 0; e < 4; ++e) {
        float4 kk = *(const float4*)&Kt[s][q4 * 16 + e * 4];
        acc[e * 4 + 0] += m * kk.x; acc[e * 4 + 1] += m * kk.y;
        acc[e * 4 + 2] += m * kk.z; acc[e * 4 + 3] += m * kk.w;
      }
    }
#pragma unroll
    for (int e = 0; e < 4; ++e) {
      float4 wv = {acc[e * 4 + 0], acc[e * 4 + 1], acc[e * 4 + 2], acc[e * 4 + 3]};
      *(float4*)&Wbuf[(size_t)u * 4096 + tr * 64 + q4 * 16 + e * 4] = wv;
    }
  }
  {
    float acc[16];
#pragma unroll
    for (int i = 0; i < 16; ++i) acc[i] = 0.f;
    for (int s = 0; s < 64; ++s) {
      float m = Mm[tr][s] * bb[s];
#pragma unroll
      for (int e = 0; e < 4; ++e) {
        float4 vv = *(const float4*)&Vb[s][q4 * 16 + e * 4];
        acc[e * 4 + 0] += m * vv.x; acc[e * 4 + 1] += m * vv.y;
        acc[e * 4 + 2] += m * vv.z; acc[e * 4 + 3] += m * vv.w;
      }
    }
#pragma unroll
    for (int e = 0; e < 4; ++e) {
      float4 rv = {acc[e * 4 + 0], acc[e * 4 + 1], acc[e * 4 + 2], acc[e * 4 + 3]};
      *(float4*)&Rbuf[(size_t)u * 4096 + tr * 64 + q4 * 16 + e * 4] = rv;
    }
  }
}

// ---------------- chunked serial scan ----------------
// 512 threads = 8 waves.  Thread = (tr 0..63, q8 0..7); owns 2 cols {2q8, 2q8+1}
// of the 64x16 vs-slice.  All per-chunk operands stored so inner loops read
// contiguous float4 rows:
//   Wb[t][kd], Pb[t][s], Qh[t][kd] (pre-scaled by exp(c_t)),
//   Kt[kd][t]  (transposed + pre-scaled by exp(c63-c_t)),
//   St[v][kd]  (S^T state), Dt[v][t] (D^T workspace).
__global__ __launch_bounds__(512) void chunk_scan_kernel(
    const float* __restrict__ mix, const float* __restrict__ Wbuf,
    const float* __restrict__ Pbuf, const float* __restrict__ Rbuf,
    const float* __restrict__ cbuf, float* __restrict__ o) {
  __shared__ float Wb[64][68], Pb[64][68], Qh[64][68], Kt[64][68];
  __shared__ float St[16][68], Dt[16][68];
  __shared__ float cs[64];

  const int bid = blockIdx.x;
  const int vs = bid & 3, hv = (bid >> 2) & 31, b = bid >> 7;
  const int hk = hv >> 2;
  const int bh = b * 32 + hv;
  const int ubase = bh * 16;
  const int tid = threadIdx.x;
  const int tr = tid >> 3, q8 = tid & 7;
  const int c0 = q8 * 2, c1 = q8 * 2 + 1;

  // zero S^T state
  for (int i = tid; i < 16 * 68; i += 512) (&St[0][0])[i] = 0.f;

  float4 WN[2], PN[2], KN[2], QN[2];
  float2 RN;
  float cN = 0.f;
  float e63c = 1.f;

#define ISSUE_LOADS(c)                                                          \
  {                                                                             \
    size_t uu = (size_t)(ubase + (c));                                          \
    _Pragma("unroll") for (int i = 0; i < 2; ++i) {                             \
      WN[i] = ((const float4*)(Wbuf + uu * 4096))[tid + 512 * i];               \
      PN[i] = ((const float4*)(Pbuf + uu * 4096))[tid + 512 * i];               \
    }                                                                           \
    const float* mrow = mix + (size_t)(b * 1024 + (c) * 64 + tr) * 3072;        \
    _Pragma("unroll") for (int e = 0; e < 2; ++e) {                             \
      KN[e] = *(const float4*)(mrow + 512 + hk * 64 + q8 * 8 + e * 4);          \
      QN[e] = *(const float4*)(mrow + hk * 64 + q8 * 8 + e * 4);                \
    }                                                                           \
    RN = *(const float2*)(Rbuf + uu * 4096 + tr * 64 + vs * 16 + q8 * 2);       \
    if (tid < 64) cN = cbuf[uu * 64 + tid];                                     \
  }

  // stage W,P,cs (pre-barrier); then scale+write Qh,Kt (post-barrier).
  // e63c (register) carries exp(cs[63]) of the staged chunk into its S-update.
#define COMMIT()                                                                \
  {                                                                             \
    _Pragma("unroll") for (int i = 0; i < 2; ++i) {                             \
      int flat = (tid + 512 * i) * 4;                                           \
      int rr = flat >> 6, cc = flat & 63;                                       \
      *(float4*)&Wb[rr][cc] = WN[i];                                            \
      *(float4*)&Pb[rr][cc] = PN[i];                                            \
    }                                                                           \
    if (tid < 64) cs[tid] = cN;                                                 \
    __syncthreads();                                                            \
    float csv = cs[tr], cs63 = cs[63];                                          \
    float sQv = __expf(csv), sKv = __expf(cs63 - csv);                          \
    e63c = __expf(cs63);                                                        \
    float4 qa, qb;                                                              \
    qa.x = QN[0].x * sQv; qa.y = QN[0].y * sQv;                                 \
    qa.z = QN[0].z * sQv; qa.w = QN[0].w * sQv;                                 \
    qb.x = QN[1].x * sQv; qb.y = QN[1].y * sQv;                                 \
    qb.z = QN[1].z * sQv; qb.w = QN[1].w * sQv;                                 \
    *(float4*)&Qh[tr][q8 * 8] = qa;                                             \
    *(float4*)&Qh[tr][q8 * 8 + 4] = qb;                                         \
    Kt[q8 * 8 + 0][tr] = KN[0].x * sKv;                                         \
    Kt[q8 * 8 + 1][tr] = KN[0].y * sKv;                                         \
    Kt[q8 * 8 + 2][tr] = KN[0].z * sKv;                                         \
    Kt[q8 * 8 + 3][tr] = KN[0].w * sKv;                                         \
    Kt[q8 * 8 + 4][tr] = KN[1].x * sKv;                                         \
    Kt[q8 * 8 + 5][tr] = KN[1].y * sKv;                                         \
    Kt[q8 * 8 + 6][tr] = KN[1].z * sKv;                                         \
    Kt[q8 * 8 + 7][tr] = KN[1].w * sKv;                                         \
  }

  ISSUE_LOADS(0);
  COMMIT();
  float2 Rv = RN;

  for (int c = 0; c < 16; ++c) {
    if (c < 15) ISSUE_LOADS(c + 1);
    // ---- D[t][v] = R - W @ S : acc over kd, contiguous in Wb row / St row ----
    float2 acc = Rv;
#pragma unroll 4
    for (int k = 0; k < 64; k += 4) {
      float4 w4 = *(const float4*)&Wb[tr][k];
      float4 sa = *(const float4*)&St[c0][k];
      float4 sb = *(const float4*)&St[c1][k];
      acc.x -= w4.x * sa.x + w4.y * sa.y + w4.z * sa.z + w4.w * sa.w;
      acc.y -= w4.x * sb.x + w4.y * sb.y + w4.z * sb.z + w4.w * sb.w;
    }
    Dt[c0][tr] = acc.x;
    Dt[c1][tr] = acc.y;
    __syncthreads();
    // ---- O[t][v] = P @ D + Qh @ S ----
    {
      float2 ao = {0.f, 0.f};
#pragma unroll 4
      for (int i = 0; i < 64; i += 4) {
        float4 p4 = *(const float4*)&Pb[tr][i];
        float4 q4 = *(const float4*)&Qh[tr][i];
        float4 da = *(const float4*)&Dt[c0][i];
        float4 db = *(const float4*)&Dt[c1][i];
        float4 sa = *(const float4*)&St[c0][i];
        float4 sb = *(const float4*)&St[c1][i];
        ao.x += p4.x * da.x + p4.y * da.y + p4.z * da.z + p4.w * da.w
              + q4.x * sa.x + q4.y * sa.y + q4.z * sa.z + q4.w * sa.w;
        ao.y += p4.x * db.x + p4.y * db.y + p4.z * db.z + p4.w * db.w
              + q4.x * sb.x + q4.y * sb.y + q4.z * sb.z + q4.w * sb.w;
      }
      *(float2*)&o[((size_t)(bh * 4 + vs) * 1024 + c * 64 + tr) * 16 + q8 * 2] = ao;
    }
    __syncthreads();
    // ---- S^T[v][kd] = e63*S^T + (Kt @ D^T-style row dot) ----
    {
      float sx = St[c0][tr] * e63c;
      float sy = St[c1][tr] * e63c;
#pragma unroll 4
      for (int t = 0; t < 64; t += 4) {
        float4 k4 = *(const float4*)&Kt[tr][t];
        float4 da = *(const float4*)&Dt[c0][t];
        float4 db = *(const float4*)&Dt[c1][t];
        sx += k4.x * da.x + k4.y * da.y + k4.z * da.z + k4.w * da.w;
        sy += k4.x * db.x + k4.y * db.y + k4.z * db.z + k4.w * db.w;
      }
      St[c0][tr] = sx;
      St[c1][tr] = sy;
    }
    if (c < 15) {
      COMMIT();   // internal barrier also orders St/Dt reuse across chunks
      Rv = RN;
    }
  }
#undef ISSUE_LOADS
#undef COMMIT
}

// ---------------- rmsnorm * norm_w * silu(z), -> bf16 ----------------
// reads o in block-local layout o[(bh*4+vs)][t][16]; writes on[bt][hv*64+d] (standard)
__global__ __launch_bounds__(256) void rms_gate_kernel(const float* __restrict__ o,
                                                       const float* __restrict__ qkvz,
                                                       const float* __restrict__ norm_w,
                                                       short* __restrict__ on) {
  int bid = blockIdx.x;            // (bh)*256 + tgroup
  int bh = bid >> 8;               // b*32+hv
  int tg = bid & 255;
  int b = bh >> 5, hv = bh & 31;
  int t = tg * 4 + (threadIdx.x >> 6);
  int d = threadIdx.x & 63;
  int bt = b * 1024 + t;
  int hk = hv >> 2, vp = hv & 3;
  float x = o[((size_t)(bh * 4 + (d >> 4)) * 1024 + t) * 16 + (d & 15)];
  float ss = x * x;
  ss += __shfl_xor(ss, 1);
  ss += __shfl_xor(ss, 2);
  ss += __shfl_xor(ss, 4);
  ss += __shfl_xor(ss, 8);
  ss += __shfl_xor(ss, 16);
  ss += __shfl_xor(ss, 32);
  float sc = rsqrtf(ss * (1.f / 64.f) + 1e-5f);
  float z = qkvz[(size_t)bt * 5184 + hk * 640 + 384 + vp * 64 + d];
  float val = x * sc * norm_w[d] * (z / (1.f + __expf(-z)));
  on[((size_t)bt * 32 + hv) * 64 + d] = f2bf(val);
}

// ---------------- launch ----------------
extern "C" void kernel_launch(void* const* d_in, const int* in_sizes, int n_in,
                              void* d_out, int out_size, void* d_ws, size_t ws_size,
                              hipStream_t stream) {
  const float* hidden = (const float*)d_in[0];
  const float* W_qkvz = (const float*)d_in[1];
  const float* W_ba = (const float*)d_in[2];
  const float* conv_w = (const float*)d_in[3];
  const float* dt_bias = (const float*)d_in[4];
  const float* A_log = (const float*)d_in[5];
  const float* norm_w = (const float*)d_in[6];
  const float* W_out = (const float*)d_in[7];
  float* out = (float*)d_out;

  char* ws = (char*)d_ws;
  short* A_bf = (short*)(ws + 0);                // 16,777,216
  short* Wt1 = (short*)(ws + 16777216);          // 42,991,616  [5248][4096] (pad)
  short* Wt2 = (short*)(ws + 59768832);          // 16,777,216  [4096][2048]
  float* qkvz = (float*)(ws + 76546048);         // 42,467,328  [2048][5184]
  float* mix = (float*)(ws + 119013376);         // 25,165,824  [2048][3072]
  float* gbuf = (float*)(ws + 144179200);        //    262,144  [2048][32]
  float* beta = (float*)(ws + 144441344);        //    262,144
  float* o = (float*)(ws + 144703488);           // 16,777,216  [256][1024][16] block-local
  short* on = (short*)(ws + 161480704);          //  8,388,608  [2048][2048]
  float* Wbuf = (float*)(ws + 169869312);        // 16,777,216  [1024][64][64]
  float* Pbuf = (float*)(ws + 186646528);        // 16,777,216
  float* Rbuf = (float*)(ws + 203423744);        // 16,777,216
  float* cbuf = (float*)(ws + 220200960);        //    262,144  [1024][64]

  to_bf16_kernel<<<8192, 256, 0, stream>>>(hidden, A_bf);
  transpose_w1<<<dim3(164, 128), 256, 0, stream>>>(W_qkvz, W_ba, Wt1);
  transpose_w2<<<dim3(128, 64), 256, 0, stream>>>(W_out, Wt2);
  // GEMM1: 16x41 tiles = 656 blocks (656%8==0 -> bijective XCD swizzle);
  // Wt1 padded to 5248 rows so staging of the last tile stays in-bounds.
  gemm128p<true><<<656, 256, 0, stream>>>(A_bf, Wt1, qkvz, 5184, 4096, 16);
  conv_kernel<<<2048, 256, 0, stream>>>(qkvz, conv_w, mix);
  gate_kernel<<<256, 256, 0, stream>>>(qkvz, dt_bias, A_log, gbuf, beta);
  precompute_kernel<<<1024, 256, 0, stream>>>(mix, gbuf, beta, Wbuf, Pbuf, Rbuf, cbuf);
  chunk_scan_kernel<<<256, 512, 0, stream>>>(mix, Wbuf, Pbuf, Rbuf, cbuf, o);
  rms_gate_kernel<<<16384, 256, 0, stream>>>(o, qkvz, norm_w, on);
  // GEMM2: 16x32 tiles = 512 blocks = exactly 2/CU.
  gemm128p<false><<<512, 256, 0, stream>>>(on, Wt2, out, 4096, 2048, 16);
}